// Round 25
// baseline (99049.261 us; speedup 1.0000x reference)
//
#include <hip/hip_runtime.h>
#include <hip/hip_bf16.h>

// ---- problem constants ----
constexpr int T = 2048, HID = 2048;
constexpr int HQ = 16, HKV = 2, D = 128, G = 8;
constexpr int KER = 32, SEL = 64, TOPN = 16, WIN = 512;
constexpr int NC = T / KER;
constexpr int S  = T / SEL;
constexpr float SCALE = 0.08838834764831845f;
constexpr float NEGF = -1e30f;

// ===== naive NT GEMM, weights (out,in) row-major =====
__global__ void naive_gemm_f32(const float* __restrict__ A, const float* __restrict__ Bm,
                               const float* __restrict__ bias, float* __restrict__ C,
                               int N, int K) {
    int n = blockIdx.x * 256 + threadIdx.x;
    int m = blockIdx.y;
    if (n >= N) return;
    const float* a = A + (size_t)m * K;
    const float* b = Bm + (size_t)n * K;
    float acc = bias ? bias[n] : 0.f;
    for (int k = 0; k < K; ++k) acc += a[k] * b[k];
    C[(size_t)m * N + n] = acc;
}

// ===== final GEMM: d_out is FLOAT32; harness reads high 16 bits as bf16 =====
// Pre-round to bf16 (RNE) so the high-half readback is the correctly-rounded value.
__global__ void final_gemm_f32out(const float* __restrict__ A, const float* __restrict__ Bm,
                                  float* __restrict__ C, int N, int K) {
    int n = blockIdx.x * 256 + threadIdx.x;
    int m = blockIdx.y;
    if (n >= N) return;
    const float* a = A + (size_t)m * K;
    const float* b = Bm + (size_t)n * K;
    float acc = 0.f;
    for (int k = 0; k < K; ++k) acc += a[k] * b[k];
    C[(size_t)m * N + n] = __bfloat162float(__float2bfloat16(acc));
}

// ================= RoPE (in-place), x: [T][H][D] ======
__global__ void rope_kernel(float* __restrict__ x, const float* __restrict__ cosb,
                            const float* __restrict__ sinb, int H) {
    int idx = blockIdx.x * blockDim.x + threadIdx.x;
    if (idx >= T * H * 64) return;
    int d = idx & 63;
    int th = idx >> 6;
    int h = th % H, t = th / H;
    float c0 = cosb[t * D + d],      s0 = sinb[t * D + d];
    float c1 = cosb[t * D + d + 64], s1 = sinb[t * D + d + 64];
    float* p = x + ((size_t)t * H + h) * D;
    float x0 = p[d], x1 = p[d + 64];
    p[d]      = x0 * c0 - x1 * s0;
    p[d + 64] = x1 * c1 + x0 * s1;
}

// ================= compression =================
__global__ void compress_kernel(const float* __restrict__ k, const float* __restrict__ v,
                                const float* __restrict__ wck, const float* __restrict__ wcv,
                                float* __restrict__ k_cmp, float* __restrict__ v_cmp) {
    int idx = blockIdx.x * blockDim.x + threadIdx.x;
    if (idx >= NC * HKV * D) return;
    int d = idx % D;
    int h = (idx / D) % HKV;
    int n = idx / (D * HKV);
    float ak = 0.f, av = 0.f;
    for (int j = 0; j < KER; ++j) {
        size_t off = ((size_t)(n * KER + j) * HKV + h) * D + d;
        ak += k[off] * wck[j];
        av += v[off] * wcv[j];
    }
    k_cmp[idx] = ak;
    v_cmp[idx] = av;
}

// ================= compressed attention =================
__global__ void cmp_attn_naive(const float* __restrict__ q, const float* __restrict__ k_cmp,
                               const float* __restrict__ v_cmp, float* __restrict__ p_cmp,
                               float* __restrict__ o_cmp) {
    int idx = blockIdx.x * 256 + threadIdx.x;
    if (idx >= T * HQ) return;
    int h = idx % HQ, t = idx / HQ;
    int kh = h / G;
    const float* qp = q + (size_t)idx * D;
    int nvis = (t >= KER - 1) ? ((t - (KER - 1)) / KER + 1) : 0;
    float sc[NC];
    float mx = -3e38f;
    for (int n = 0; n < nvis; ++n) {
        const float* kp = k_cmp + ((size_t)n * HKV + kh) * D;
        float a = 0.f;
        for (int d = 0; d < D; ++d) a += qp[d] * kp[d];
        a *= SCALE;
        sc[n] = a;
        mx = fmaxf(mx, a);
    }
    float sum = 0.f;
    for (int n = 0; n < nvis; ++n) { sc[n] = expf(sc[n] - mx); sum += sc[n]; }
    float inv = (sum > 0.f) ? 1.f / sum : 0.f;
    for (int n = 0; n < NC; ++n) {
        float p = (n < nvis) ? sc[n] * inv : 0.f;
        if (n < nvis) sc[n] = p;
        p_cmp[((size_t)h * T + t) * NC + n] = p;
    }
    for (int d = 0; d < D; ++d) {
        float o = 0.f;
        for (int n = 0; n < nvis; ++n)
            o += sc[n] * v_cmp[((size_t)n * HKV + kh) * D + d];
        o_cmp[(size_t)idx * D + d] = o;
    }
}

// ================= block scores + top-16 selection =================
__global__ void select_kernel(const float* __restrict__ p_cmp, unsigned* __restrict__ selmask) {
    int idx = blockIdx.x * blockDim.x + threadIdx.x;
    if (idx >= HKV * T) return;
    int t = idx % T, kh = idx / T;
    float bs[S];
    for (int s = 0; s < S; ++s) bs[s] = 0.f;
    for (int g = 0; g < G; ++g) {
        const float* pp = p_cmp + (((size_t)(kh * G + g)) * T + t) * NC;
        for (int s = 0; s < S; ++s) bs[s] += pp[2 * s] + pp[2 * s + 1];
    }
    int cur = t / SEL;
    for (int s = 0; s < S; ++s) {
        bool vis = (s * SEL <= t);
        bool force = (s == 0) || (s == cur);
        bs[s] = vis ? (bs[s] + (force ? 1e6f : 0.f)) : NEGF;
    }
    unsigned chosen = 0;
    for (int it = 0; it < TOPN; ++it) {
        float best = -3e38f;
        int bj = 0;
        for (int s = 0; s < S; ++s) {
            bool free_s = !((chosen >> s) & 1);
            if (free_s && bs[s] > best) { best = bs[s]; bj = s; }
        }
        chosen |= 1u << bj;
    }
    selmask[idx] = chosen;
}

// ================= selected / windowed attention (naive two-pass) ====
template<int MODE>
__global__ void attn_naive(const float* __restrict__ q, const float* __restrict__ k,
                           const float* __restrict__ v, const unsigned* __restrict__ selmask,
                           float* __restrict__ outp) {
    int idx = blockIdx.x * 256 + threadIdx.x;
    if (idx >= T * HQ) return;
    int h = idx % HQ, t = idx / HQ;
    int kh = h / G;
    const float* qp = q + (size_t)idx * D;
    unsigned msk = (MODE == 0) ? selmask[kh * T + t] : 0u;
    int lo = t - WIN + 1; if (lo < 0) lo = 0;

    float m = -3e38f;
    if (MODE == 0) {
        for (int s = 0; s < S; ++s) {
            if (!((msk >> s) & 1)) continue;
            int j0 = s * SEL; if (j0 > t) continue;
            int j1 = j0 + SEL - 1; if (j1 > t) j1 = t;
            for (int j = j0; j <= j1; ++j) {
                const float* kp = k + ((size_t)j * HKV + kh) * D;
                float a = 0.f;
                for (int d = 0; d < D; ++d) a += qp[d] * kp[d];
                m = fmaxf(m, a * SCALE);
            }
        }
    } else {
        for (int j = lo; j <= t; ++j) {
            const float* kp = k + ((size_t)j * HKV + kh) * D;
            float a = 0.f;
            for (int d = 0; d < D; ++d) a += qp[d] * kp[d];
            m = fmaxf(m, a * SCALE);
        }
    }
    float l = 0.f;
    float o[D];
    for (int d = 0; d < D; ++d) o[d] = 0.f;
    if (MODE == 0) {
        for (int s = 0; s < S; ++s) {
            if (!((msk >> s) & 1)) continue;
            int j0 = s * SEL; if (j0 > t) continue;
            int j1 = j0 + SEL - 1; if (j1 > t) j1 = t;
            for (int j = j0; j <= j1; ++j) {
                const float* kp = k + ((size_t)j * HKV + kh) * D;
                float a = 0.f;
                for (int d = 0; d < D; ++d) a += qp[d] * kp[d];
                float p = expf(a * SCALE - m);
                l += p;
                const float* vp = v + ((size_t)j * HKV + kh) * D;
                for (int d = 0; d < D; ++d) o[d] += p * vp[d];
            }
        }
    } else {
        for (int j = lo; j <= t; ++j) {
            const float* kp = k + ((size_t)j * HKV + kh) * D;
            float a = 0.f;
            for (int d = 0; d < D; ++d) a += qp[d] * kp[d];
            float p = expf(a * SCALE - m);
            l += p;
            const float* vp = v + ((size_t)j * HKV + kh) * D;
            for (int d = 0; d < D; ++d) o[d] += p * vp[d];
        }
    }
    float inv = 1.f / l;
    for (int d = 0; d < D; ++d) outp[(size_t)idx * D + d] = o[d] * inv;
}

// ================= gates + combine ============
__global__ void gate_naive(const float* __restrict__ q, const float* __restrict__ Wg,
                           const float* __restrict__ o_cmp, const float* __restrict__ o_sel,
                           const float* __restrict__ o_win, float* __restrict__ o_comb) {
    int idx = blockIdx.x * 256 + threadIdx.x;
    if (idx >= T * HQ) return;
    int h = idx % HQ;
    const float* qp = q + (size_t)idx * D;
    const float* wg = Wg + (size_t)h * D * 3;
    float g0 = 0.f, g1 = 0.f, g2 = 0.f;
    for (int d = 0; d < D; ++d) {
        float qv = qp[d];
        g0 += qv * wg[d * 3 + 0];
        g1 += qv * wg[d * 3 + 1];
        g2 += qv * wg[d * 3 + 2];
    }
    g0 = 1.f / (1.f + expf(-g0));
    g1 = 1.f / (1.f + expf(-g1));
    g2 = 1.f / (1.f + expf(-g2));
    size_t base = (size_t)idx * D;
    for (int d = 0; d < D; ++d)
        o_comb[base + d] = g0 * o_cmp[base + d] + g1 * o_sel[base + d] + g2 * o_win[base + d];
}

// ================= launcher ==============
extern "C" void kernel_launch(void* const* d_in, const int* in_sizes, int n_in,
                              void* d_out, int out_size, void* d_ws, size_t ws_size,
                              hipStream_t stream) {
    const float* hs   = (const float*)d_in[0];
    const float* cosb = (const float*)d_in[1];
    const float* sinb = (const float*)d_in[2];
    const float* Wq   = (const float*)d_in[3];
    const float* bq   = (const float*)d_in[4];
    const float* Wk   = (const float*)d_in[5];
    const float* bk   = (const float*)d_in[6];
    const float* Wv   = (const float*)d_in[7];
    const float* bv   = (const float*)d_in[8];
    const float* Wo   = (const float*)d_in[9];
    const float* w_ck = (const float*)d_in[10];
    const float* w_cv = (const float*)d_in[11];
    const float* Wg   = (const float*)d_in[12];
    float* out = (float*)d_out;   // FLOAT32 output buffer (high 16 bits read as bf16)

    float* ws = (float*)d_ws;
    size_t off = 0;
    float* q      = ws + off; off += (size_t)T * HQ * D;
    float* k      = ws + off; off += (size_t)T * HKV * D;
    float* v      = ws + off; off += (size_t)T * HKV * D;
    float* k_cmp  = ws + off; off += (size_t)NC * HKV * D;
    float* v_cmp  = ws + off; off += (size_t)NC * HKV * D;
    float* p_cmp  = ws + off; off += (size_t)HQ * T * NC;
    float* o_cmp  = ws + off; off += (size_t)T * HQ * D;
    float* o_sel  = ws + off; off += (size_t)T * HQ * D;
    float* o_win  = ws + off; off += (size_t)T * HQ * D;
    unsigned* selmask = (unsigned*)(ws + off);

    naive_gemm_f32<<<dim3((HQ * D) / 256, T), 256, 0, stream>>>(hs, Wq, bq, q, HQ * D, HID);
    naive_gemm_f32<<<dim3((HKV * D) / 256, T), 256, 0, stream>>>(hs, Wk, bk, k, HKV * D, HID);
    naive_gemm_f32<<<dim3((HKV * D) / 256, T), 256, 0, stream>>>(hs, Wv, bv, v, HKV * D, HID);
    rope_kernel<<<(T * HQ * 64) / 256, 256, 0, stream>>>(q, cosb, sinb, HQ);
    rope_kernel<<<(T * HKV * 64) / 256, 256, 0, stream>>>(k, cosb, sinb, HKV);
    compress_kernel<<<(NC * HKV * D) / 256, 256, 0, stream>>>(k, v, w_ck, w_cv, k_cmp, v_cmp);
    cmp_attn_naive<<<(T * HQ) / 256, 256, 0, stream>>>(q, k_cmp, v_cmp, p_cmp, o_cmp);
    select_kernel<<<(HKV * T) / 256, 256, 0, stream>>>(p_cmp, selmask);
    attn_naive<0><<<(T * HQ) / 256, 256, 0, stream>>>(q, k, v, selmask, o_sel);
    attn_naive<1><<<(T * HQ) / 256, 256, 0, stream>>>(q, k, v, nullptr, o_win);
    gate_naive<<<(T * HQ) / 256, 256, 0, stream>>>(q, Wg, o_cmp, o_sel, o_win, o_cmp);
    final_gemm_f32out<<<dim3(HID / 256, T), 256, 0, stream>>>(o_cmp, Wo, out, HID, HQ * D);
}

// Round 26
// 4462.514 us; speedup vs baseline: 22.1958x; 22.1958x over previous
//
#include <hip/hip_runtime.h>
#include <hip/hip_bf16.h>

// ---- problem constants ----
constexpr int T = 2048, HID = 2048;
constexpr int HQ = 16, HKV = 2, D = 128, G = 8;
constexpr int KER = 32, SEL = 64, TOPN = 16, WIN = 512;
constexpr int NC = T / KER;
constexpr int S  = T / SEL;
constexpr float SCALE = 0.08838834764831845f;
constexpr float NEGF = -1e30f;

// ================= tiled NT GEMM: C[M,N] = A[M,K] @ W[N,K]^T (+bias) =================
// OUT_MODE: 0 = raw f32, 1 = f32 pre-rounded to bf16 (for the f32-viewed-as-bf16 output)
#define BM 64
#define BN 64
#define BK 32

template<int OUT_MODE, bool HAS_BIAS>
__global__ __launch_bounds__(256)
void gemm_tiled(const float* __restrict__ A, const float* __restrict__ Bm,
                const float* __restrict__ bias, float* __restrict__ C,
                int M, int N, int K) {
    __shared__ float As[BK][BM + 1];
    __shared__ float Bs[BK][BN + 1];
    const int m0 = blockIdx.y * BM, n0 = blockIdx.x * BN;
    const int tid = threadIdx.x;
    const int tx = tid % 16, ty = tid / 16;
    float acc[4][4] = {};
    for (int k0 = 0; k0 < K; k0 += BK) {
#pragma unroll
        for (int i = 0; i < 2; ++i) {
            int idx = tid + i * 256;          // 0..511
            int r = idx >> 3;                  // tile row
            int c4 = idx & 7;                  // which float4 of BK
            float4 a = *reinterpret_cast<const float4*>(&A[(size_t)(m0 + r) * K + k0 + c4 * 4]);
            As[c4 * 4 + 0][r] = a.x; As[c4 * 4 + 1][r] = a.y;
            As[c4 * 4 + 2][r] = a.z; As[c4 * 4 + 3][r] = a.w;
            float4 b = *reinterpret_cast<const float4*>(&Bm[(size_t)(n0 + r) * K + k0 + c4 * 4]);
            Bs[c4 * 4 + 0][r] = b.x; Bs[c4 * 4 + 1][r] = b.y;
            Bs[c4 * 4 + 2][r] = b.z; Bs[c4 * 4 + 3][r] = b.w;
        }
        __syncthreads();
#pragma unroll
        for (int kk = 0; kk < BK; ++kk) {
            float a[4], b[4];
#pragma unroll
            for (int i = 0; i < 4; ++i) a[i] = As[kk][ty * 4 + i];
#pragma unroll
            for (int j = 0; j < 4; ++j) b[j] = Bs[kk][tx * 4 + j];
#pragma unroll
            for (int i = 0; i < 4; ++i)
#pragma unroll
                for (int j = 0; j < 4; ++j) acc[i][j] += a[i] * b[j];
        }
        __syncthreads();
    }
#pragma unroll
    for (int i = 0; i < 4; ++i) {
        int m = m0 + ty * 4 + i;
#pragma unroll
        for (int j = 0; j < 4; ++j) {
            int n = n0 + tx * 4 + j;
            float val = acc[i][j];
            if (HAS_BIAS) val += bias[n];
            if (OUT_MODE == 1) val = __bfloat162float(__float2bfloat16(val));
            C[(size_t)m * N + n] = val;
        }
    }
}

// ================= RoPE (in-place), x: [T][H][D] ==============
__global__ void rope_kernel(float* __restrict__ x, const float* __restrict__ cosb,
                            const float* __restrict__ sinb, int H) {
    int idx = blockIdx.x * blockDim.x + threadIdx.x;
    if (idx >= T * H * 64) return;
    int d = idx & 63;
    int th = idx >> 6;
    int h = th % H, t = th / H;
    float c0 = cosb[t * D + d],      s0 = sinb[t * D + d];
    float c1 = cosb[t * D + d + 64], s1 = sinb[t * D + d + 64];
    float* p = x + ((size_t)t * H + h) * D;
    float x0 = p[d], x1 = p[d + 64];
    p[d]      = x0 * c0 - x1 * s0;
    p[d + 64] = x1 * c1 + x0 * s1;
}

// ================= compression ==============
__global__ void compress_kernel(const float* __restrict__ k, const float* __restrict__ v,
                                const float* __restrict__ wck, const float* __restrict__ wcv,
                                float* __restrict__ k_cmp, float* __restrict__ v_cmp) {
    int idx = blockIdx.x * blockDim.x + threadIdx.x;
    if (idx >= NC * HKV * D) return;
    int d = idx % D;
    int h = (idx / D) % HKV;
    int n = idx / (D * HKV);
    float ak = 0.f, av = 0.f;
#pragma unroll 8
    for (int j = 0; j < KER; ++j) {
        size_t off = ((size_t)(n * KER + j) * HKV + h) * D + d;
        ak += k[off] * wck[j];
        av += v[off] * wcv[j];
    }
    k_cmp[idx] = ak;
    v_cmp[idx] = av;
}

// ================= compressed attention (wave per (t,h)) ==============
__global__ __launch_bounds__(256)
void cmp_attn_wave(const float* __restrict__ q, const float* __restrict__ k_cmp,
                   const float* __restrict__ v_cmp, float* __restrict__ p_cmp,
                   float* __restrict__ o_cmp) {
    int wid = blockIdx.x * 4 + (threadIdx.x >> 6);
    int lane = threadIdx.x & 63;
    int t = wid / HQ, h = wid % HQ;
    int kh = h / G;
    int n = lane;
    bool vis = (t >= KER * n + KER - 1);
    const float4* qp = reinterpret_cast<const float4*>(q + ((size_t)t * HQ + h) * D);
    const float4* kp = reinterpret_cast<const float4*>(k_cmp + ((size_t)n * HKV + kh) * D);
    float acc = 0.f;
#pragma unroll
    for (int i = 0; i < 32; ++i) {
        float4 a = qp[i], b = kp[i];
        acc += a.x * b.x + a.y * b.y + a.z * b.z + a.w * b.w;
    }
    float s = vis ? acc * SCALE : NEGF;
    float mx = s;
#pragma unroll
    for (int off = 32; off; off >>= 1) mx = fmaxf(mx, __shfl_xor(mx, off));
    float e = vis ? expf(s - mx) : 0.f;
    float sum = e;
#pragma unroll
    for (int off = 32; off; off >>= 1) sum += __shfl_xor(sum, off);
    float p = (sum > 0.f) ? (e / sum) : 0.f;
    p_cmp[((size_t)h * T + t) * NC + n] = p;
    float o0 = 0.f, o1 = 0.f;
    int d0 = lane, d1 = lane + 64;
    for (int nn = 0; nn < NC; ++nn) {
        float pn = __shfl(p, nn);
        const float* vp = v_cmp + ((size_t)nn * HKV + kh) * D;
        o0 += pn * vp[d0];
        o1 += pn * vp[d1];
    }
    float* op = o_cmp + ((size_t)t * HQ + h) * D;
    op[d0] = o0;
    op[d1] = o1;
}

// ================= block scores + top-16 selection ==============
__global__ void select_kernel(const float* __restrict__ p_cmp, unsigned* __restrict__ selmask) {
    int idx = blockIdx.x * blockDim.x + threadIdx.x;
    if (idx >= HKV * T) return;
    int t = idx % T, kh = idx / T;
    float bs[S];
#pragma unroll
    for (int s = 0; s < S; ++s) bs[s] = 0.f;
    for (int g = 0; g < G; ++g) {
        const float* pp = p_cmp + (((size_t)(kh * G + g)) * T + t) * NC;
#pragma unroll
        for (int s = 0; s < S; ++s) bs[s] += pp[2 * s] + pp[2 * s + 1];
    }
    int cur = t / SEL;
#pragma unroll
    for (int s = 0; s < S; ++s) {
        bool vis = (s * SEL <= t);
        bool force = (s == 0) || (s == cur);
        bs[s] = vis ? (bs[s] + (force ? 1e6f : 0.f)) : NEGF;
    }
    unsigned chosen = 0;
    for (int it = 0; it < TOPN; ++it) {
        float best = -3e38f;
        int bj = 0;
#pragma unroll
        for (int s = 0; s < S; ++s) {
            bool free_s = !((chosen >> s) & 1);
            if (free_s && bs[s] > best) { best = bs[s]; bj = s; }
        }
        chosen |= 1u << bj;
    }
    selmask[idx] = chosen;
}

// ================= selected / windowed attention (wave per (t,h), online softmax) ====
template<int MODE>  // 0 = selected blocks, 1 = sliding window
__global__ __launch_bounds__(256)
void attn_wave(const float* __restrict__ q, const float* __restrict__ k,
               const float* __restrict__ v, const unsigned* __restrict__ selmask,
               float* __restrict__ out) {
    int wid = blockIdx.x * 4 + (threadIdx.x >> 6);
    int lane = threadIdx.x & 63;
    int t = wid / HQ, h = wid % HQ;
    int kh = h / G;
    const float4* qp = reinterpret_cast<const float4*>(q + ((size_t)t * HQ + h) * D);
    float m = NEGF, lsum = 0.f, o0 = 0.f, o1 = 0.f;
    int d0 = lane, d1 = lane + 64;

    auto process_chunk = [&](int s, int jlo) {
        int j = s * 64 + lane;
        bool ok = (j >= jlo) && (j <= t);
        float acc = 0.f;
        if (ok) {
            const float4* kp = reinterpret_cast<const float4*>(k + ((size_t)j * HKV + kh) * D);
#pragma unroll
            for (int i = 0; i < 32; ++i) {
                float4 a = qp[i], b = kp[i];
                acc += a.x * b.x + a.y * b.y + a.z * b.z + a.w * b.w;
            }
        }
        float sc = ok ? acc * SCALE : NEGF;
        float cm = sc;
#pragma unroll
        for (int off = 32; off; off >>= 1) cm = fmaxf(cm, __shfl_xor(cm, off));
        float mn = fmaxf(m, cm);
        float scale_f = expf(m - mn);   // first chunk: exp(-inf) = 0; o/lsum are 0 anyway
        o0 *= scale_f; o1 *= scale_f; lsum *= scale_f;
        float p = ok ? expf(sc - mn) : 0.f;
        float ps = p;
#pragma unroll
        for (int off = 32; off; off >>= 1) ps += __shfl_xor(ps, off);
        lsum += ps;
        m = mn;
        for (int nn = 0; nn < 64; ++nn) {
            float pn = __shfl(p, nn);
            const float* vp = v + ((size_t)(s * 64 + nn) * HKV + kh) * D;
            o0 += pn * vp[d0];
            o1 += pn * vp[d1];
        }
    };

    if (MODE == 0) {
        unsigned msk = selmask[kh * T + t];
        for (int s = 0; s < S; ++s) {
            if (((msk >> s) & 1) && s * SEL <= t) process_chunk(s, 0);
        }
    } else {
        int lo = t - WIN + 1;
        if (lo < 0) lo = 0;
        for (int s = lo / 64; s <= t / 64; ++s) process_chunk(s, lo);
    }
    float inv = 1.f / lsum;
    float* op = out + ((size_t)t * HQ + h) * D;
    op[d0] = o0 * inv;
    op[d1] = o1 * inv;
}

// ================= gates + combine (wave per (t,h)) ==============
__global__ __launch_bounds__(256)
void gate_wave(const float* __restrict__ q, const float* __restrict__ Wg,
               const float* __restrict__ o_cmp, const float* __restrict__ o_sel,
               const float* __restrict__ o_win, float* __restrict__ o_comb) {
    int wid = blockIdx.x * 4 + (threadIdx.x >> 6);
    int lane = threadIdx.x & 63;
    int t = wid / HQ, h = wid % HQ;
    const float* qp = q + ((size_t)t * HQ + h) * D;
    const float* wg = Wg + (size_t)h * D * 3;
    float g0 = 0.f, g1 = 0.f, g2 = 0.f;
#pragma unroll
    for (int r = 0; r < 2; ++r) {
        int d = lane + r * 64;
        float qv = qp[d];
        g0 += qv * wg[d * 3 + 0];
        g1 += qv * wg[d * 3 + 1];
        g2 += qv * wg[d * 3 + 2];
    }
#pragma unroll
    for (int off = 32; off; off >>= 1) {
        g0 += __shfl_xor(g0, off);
        g1 += __shfl_xor(g1, off);
        g2 += __shfl_xor(g2, off);
    }
    g0 = 1.f / (1.f + expf(-g0));
    g1 = 1.f / (1.f + expf(-g1));
    g2 = 1.f / (1.f + expf(-g2));
    size_t base = ((size_t)t * HQ + h) * D;
#pragma unroll
    for (int r = 0; r < 2; ++r) {
        size_t i = base + lane + r * 64;
        o_comb[i] = g0 * o_cmp[i] + g1 * o_sel[i] + g2 * o_win[i];
    }
}

// ================= launcher ==============
extern "C" void kernel_launch(void* const* d_in, const int* in_sizes, int n_in,
                              void* d_out, int out_size, void* d_ws, size_t ws_size,
                              hipStream_t stream) {
    const float* hs   = (const float*)d_in[0];
    const float* cosb = (const float*)d_in[1];
    const float* sinb = (const float*)d_in[2];
    const float* Wq   = (const float*)d_in[3];
    const float* bq   = (const float*)d_in[4];
    const float* Wk   = (const float*)d_in[5];
    const float* bk   = (const float*)d_in[6];
    const float* Wv   = (const float*)d_in[7];
    const float* bv   = (const float*)d_in[8];
    const float* Wo   = (const float*)d_in[9];
    const float* w_ck = (const float*)d_in[10];
    const float* w_cv = (const float*)d_in[11];
    const float* Wg   = (const float*)d_in[12];
    float* out = (float*)d_out;   // FLOAT32 output buffer (high 16 bits read as bf16)

    float* ws = (float*)d_ws;
    size_t off = 0;
    float* q      = ws + off; off += (size_t)T * HQ * D;
    float* k      = ws + off; off += (size_t)T * HKV * D;
    float* v      = ws + off; off += (size_t)T * HKV * D;
    float* k_cmp  = ws + off; off += (size_t)NC * HKV * D;
    float* v_cmp  = ws + off; off += (size_t)NC * HKV * D;
    float* p_cmp  = ws + off; off += (size_t)HQ * T * NC;
    float* o_cmp  = ws + off; off += (size_t)T * HQ * D;
    float* o_sel  = ws + off; off += (size_t)T * HQ * D;
    float* o_win  = ws + off; off += (size_t)T * HQ * D;
    unsigned* selmask = (unsigned*)(ws + off);

    // projections (tiled)
    gemm_tiled<0, true><<<dim3((HQ * D) / BN, T / BM), 256, 0, stream>>>(hs, Wq, bq, q, T, HQ * D, HID);
    gemm_tiled<0, true><<<dim3((HKV * D) / BN, T / BM), 256, 0, stream>>>(hs, Wk, bk, k, T, HKV * D, HID);
    gemm_tiled<0, true><<<dim3((HKV * D) / BN, T / BM), 256, 0, stream>>>(hs, Wv, bv, v, T, HKV * D, HID);
    // RoPE
    rope_kernel<<<(T * HQ * 64) / 256, 256, 0, stream>>>(q, cosb, sinb, HQ);
    rope_kernel<<<(T * HKV * 64) / 256, 256, 0, stream>>>(k, cosb, sinb, HKV);
    // compression
    compress_kernel<<<(NC * HKV * D) / 256, 256, 0, stream>>>(k, v, w_ck, w_cv, k_cmp, v_cmp);
    // compressed attention
    cmp_attn_wave<<<(T * HQ) / 4, 256, 0, stream>>>(q, k_cmp, v_cmp, p_cmp, o_cmp);
    // selection
    select_kernel<<<(HKV * T) / 256, 256, 0, stream>>>(p_cmp, selmask);
    // selected + window attention
    attn_wave<0><<<(T * HQ) / 4, 256, 0, stream>>>(q, k, v, selmask, o_sel);
    attn_wave<1><<<(T * HQ) / 4, 256, 0, stream>>>(q, k, v, nullptr, o_win);
    // gates + combine (in-place over o_cmp)
    gate_wave<<<(T * HQ) / 4, 256, 0, stream>>>(q, Wg, o_cmp, o_sel, o_win, o_cmp);
    // output projection (bf16 pre-rounded f32 store)
    gemm_tiled<1, false><<<dim3(HID / BN, T / BM), 256, 0, stream>>>(o_cmp, Wo, nullptr, out, T, HID, HQ * D);
}

// Round 27
// 4073.973 us; speedup vs baseline: 24.3127x; 1.0954x over previous
//
#include <hip/hip_runtime.h>
#include <hip/hip_bf16.h>

// ---- problem constants ----
constexpr int T = 2048, HID = 2048;
constexpr int HQ = 16, HKV = 2, D = 128, G = 8;
constexpr int KER = 32, SEL = 64, TOPN = 16, WIN = 512;
constexpr int NC = T / KER;
constexpr int S  = T / SEL;
constexpr float SCALE = 0.08838834764831845f;
constexpr float NEGF = -1e30f;

// ================= tiled NT GEMM: C[M,N] = A[M,K] @ W[N,K]^T (+bias) =================
#define BM 64
#define BN 64
#define BK 32

template<int OUT_MODE, bool HAS_BIAS>   // OUT_MODE 1: pre-round to bf16 (f32 buffer read as bf16 high-half)
__global__ __launch_bounds__(256)
void gemm_tiled(const float* __restrict__ A, const float* __restrict__ Bm,
                const float* __restrict__ bias, float* __restrict__ C,
                int M, int N, int K) {
    __shared__ float As[BK][BM + 1];
    __shared__ float Bs[BK][BN + 1];
    const int m0 = blockIdx.y * BM, n0 = blockIdx.x * BN;
    const int tid = threadIdx.x;
    const int tx = tid % 16, ty = tid / 16;
    float acc[4][4] = {};
    for (int k0 = 0; k0 < K; k0 += BK) {
#pragma unroll
        for (int i = 0; i < 2; ++i) {
            int idx = tid + i * 256;
            int r = idx >> 3;
            int c4 = idx & 7;
            float4 a = *reinterpret_cast<const float4*>(&A[(size_t)(m0 + r) * K + k0 + c4 * 4]);
            As[c4 * 4 + 0][r] = a.x; As[c4 * 4 + 1][r] = a.y;
            As[c4 * 4 + 2][r] = a.z; As[c4 * 4 + 3][r] = a.w;
            float4 b = *reinterpret_cast<const float4*>(&Bm[(size_t)(n0 + r) * K + k0 + c4 * 4]);
            Bs[c4 * 4 + 0][r] = b.x; Bs[c4 * 4 + 1][r] = b.y;
            Bs[c4 * 4 + 2][r] = b.z; Bs[c4 * 4 + 3][r] = b.w;
        }
        __syncthreads();
#pragma unroll
        for (int kk = 0; kk < BK; ++kk) {
            float a[4], b[4];
#pragma unroll
            for (int i = 0; i < 4; ++i) a[i] = As[kk][ty * 4 + i];
#pragma unroll
            for (int j = 0; j < 4; ++j) b[j] = Bs[kk][tx * 4 + j];
#pragma unroll
            for (int i = 0; i < 4; ++i)
#pragma unroll
                for (int j = 0; j < 4; ++j) acc[i][j] += a[i] * b[j];
        }
        __syncthreads();
    }
#pragma unroll
    for (int i = 0; i < 4; ++i) {
        int m = m0 + ty * 4 + i;
#pragma unroll
        for (int j = 0; j < 4; ++j) {
            int n = n0 + tx * 4 + j;
            float val = acc[i][j];
            if (HAS_BIAS) val += bias[n];
            if (OUT_MODE == 1) val = __bfloat162float(__float2bfloat16(val));
            C[(size_t)m * N + n] = val;
        }
    }
}

// ================= RoPE (in-place) ==============
__global__ void rope_kernel(float* __restrict__ x, const float* __restrict__ cosb,
                            const float* __restrict__ sinb, int H) {
    int idx = blockIdx.x * blockDim.x + threadIdx.x;
    if (idx >= T * H * 64) return;
    int d = idx & 63;
    int th = idx >> 6;
    int h = th % H, t = th / H;
    float c0 = cosb[t * D + d],      s0 = sinb[t * D + d];
    float c1 = cosb[t * D + d + 64], s1 = sinb[t * D + d + 64];
    float* p = x + ((size_t)t * H + h) * D;
    float x0 = p[d], x1 = p[d + 64];
    p[d]      = x0 * c0 - x1 * s0;
    p[d + 64] = x1 * c1 + x0 * s1;
}

// ================= compression ==============
__global__ void compress_kernel(const float* __restrict__ k, const float* __restrict__ v,
                                const float* __restrict__ wck, const float* __restrict__ wcv,
                                float* __restrict__ k_cmp, float* __restrict__ v_cmp) {
    int idx = blockIdx.x * blockDim.x + threadIdx.x;
    if (idx >= NC * HKV * D) return;
    int d = idx % D;
    int h = (idx / D) % HKV;
    int n = idx / (D * HKV);
    float ak = 0.f, av = 0.f;
#pragma unroll 8
    for (int j = 0; j < KER; ++j) {
        size_t off = ((size_t)(n * KER + j) * HKV + h) * D + d;
        ak += k[off] * wck[j];
        av += v[off] * wcv[j];
    }
    k_cmp[idx] = ak;
    v_cmp[idx] = av;
}

// ================= compressed attention (wave per (t,h)) ==============
__global__ __launch_bounds__(256)
void cmp_attn_wave(const float* __restrict__ q, const float* __restrict__ k_cmp,
                   const float* __restrict__ v_cmp, float* __restrict__ p_cmp,
                   float* __restrict__ o_cmp) {
    int wid = blockIdx.x * 4 + (threadIdx.x >> 6);
    int lane = threadIdx.x & 63;
    int t = wid / HQ, h = wid % HQ;
    int kh = h / G;
    int n = lane;
    bool vis = (t >= KER * n + KER - 1);
    const float4* qp = reinterpret_cast<const float4*>(q + ((size_t)t * HQ + h) * D);
    const float4* kp = reinterpret_cast<const float4*>(k_cmp + ((size_t)n * HKV + kh) * D);
    float a0 = 0.f, a1 = 0.f, a2 = 0.f, a3 = 0.f;
#pragma unroll
    for (int i = 0; i < 8; ++i) {
        float4 x0 = qp[i * 4 + 0], y0 = kp[i * 4 + 0];
        float4 x1 = qp[i * 4 + 1], y1 = kp[i * 4 + 1];
        float4 x2 = qp[i * 4 + 2], y2 = kp[i * 4 + 2];
        float4 x3 = qp[i * 4 + 3], y3 = kp[i * 4 + 3];
        a0 += x0.x * y0.x + x0.y * y0.y + x0.z * y0.z + x0.w * y0.w;
        a1 += x1.x * y1.x + x1.y * y1.y + x1.z * y1.z + x1.w * y1.w;
        a2 += x2.x * y2.x + x2.y * y2.y + x2.z * y2.z + x2.w * y2.w;
        a3 += x3.x * y3.x + x3.y * y3.y + x3.z * y3.z + x3.w * y3.w;
    }
    float acc = (a0 + a1) + (a2 + a3);
    float s = vis ? acc * SCALE : NEGF;
    float mx = s;
#pragma unroll
    for (int off = 32; off; off >>= 1) mx = fmaxf(mx, __shfl_xor(mx, off));
    float e = vis ? expf(s - mx) : 0.f;
    float sum = e;
#pragma unroll
    for (int off = 32; off; off >>= 1) sum += __shfl_xor(sum, off);
    float p = (sum > 0.f) ? (e / sum) : 0.f;
    p_cmp[((size_t)h * T + t) * NC + n] = p;
    float c00 = 0.f, c01 = 0.f, c02 = 0.f, c03 = 0.f;
    float c10 = 0.f, c11 = 0.f, c12 = 0.f, c13 = 0.f;
    int d0 = lane, d1 = lane + 64;
    for (int nn = 0; nn < NC; nn += 4) {
        float p0 = __shfl(p, nn), p1 = __shfl(p, nn + 1);
        float p2 = __shfl(p, nn + 2), p3 = __shfl(p, nn + 3);
        const float* v0 = v_cmp + ((size_t)(nn + 0) * HKV + kh) * D;
        const float* v1 = v_cmp + ((size_t)(nn + 1) * HKV + kh) * D;
        const float* v2 = v_cmp + ((size_t)(nn + 2) * HKV + kh) * D;
        const float* v3 = v_cmp + ((size_t)(nn + 3) * HKV + kh) * D;
        c00 += p0 * v0[d0]; c10 += p0 * v0[d1];
        c01 += p1 * v1[d0]; c11 += p1 * v1[d1];
        c02 += p2 * v2[d0]; c12 += p2 * v2[d1];
        c03 += p3 * v3[d0]; c13 += p3 * v3[d1];
    }
    float* op = o_cmp + ((size_t)t * HQ + h) * D;
    op[d0] = (c00 + c01) + (c02 + c03);
    op[d1] = (c10 + c11) + (c12 + c13);
}

// ================= block scores + top-16 selection ==============
__global__ void select_kernel(const float* __restrict__ p_cmp, unsigned* __restrict__ selmask) {
    int idx = blockIdx.x * blockDim.x + threadIdx.x;
    if (idx >= HKV * T) return;
    int t = idx % T, kh = idx / T;
    float bs[S];
#pragma unroll
    for (int s = 0; s < S; ++s) bs[s] = 0.f;
    for (int g = 0; g < G; ++g) {
        const float* pp = p_cmp + (((size_t)(kh * G + g)) * T + t) * NC;
#pragma unroll
        for (int s = 0; s < S; ++s) bs[s] += pp[2 * s] + pp[2 * s + 1];
    }
    int cur = t / SEL;
#pragma unroll
    for (int s = 0; s < S; ++s) {
        bool vis = (s * SEL <= t);
        bool force = (s == 0) || (s == cur);
        bs[s] = vis ? (bs[s] + (force ? 1e6f : 0.f)) : NEGF;
    }
    unsigned chosen = 0;
    for (int it = 0; it < TOPN; ++it) {
        float best = -3e38f;
        int bj = 0;
#pragma unroll
        for (int s = 0; s < S; ++s) {
            bool free_s = !((chosen >> s) & 1);
            if (free_s && bs[s] > best) { best = bs[s]; bj = s; }
        }
        chosen |= 1u << bj;
    }
    selmask[idx] = chosen;
}

// ======== selected / windowed attention: BLOCK (4 waves) per (t,h), online softmax ========
template<int MODE>  // 0 = selected blocks, 1 = sliding window
__global__ __launch_bounds__(256)
void attn_block(const float* __restrict__ q, const float* __restrict__ k,
                const float* __restrict__ v, const unsigned* __restrict__ selmask,
                float* __restrict__ out) {
    int bid = blockIdx.x;
    int t = bid / HQ, h = bid % HQ;
    int kh = h / G;
    int w = threadIdx.x >> 6;        // wave 0..3
    int lane = threadIdx.x & 63;
    const float4* qp = reinterpret_cast<const float4*>(q + ((size_t)t * HQ + h) * D);
    float m = NEGF, lsum = 0.f, o0 = 0.f, o1 = 0.f;
    int d0 = lane, d1 = lane + 64;

    auto process_chunk = [&](int s, int jlo) {
        int j = s * 64 + lane;
        bool ok = (j >= jlo) && (j <= t);
        float acc;
        {
            float a0 = 0.f, a1 = 0.f, a2 = 0.f, a3 = 0.f;
            if (ok) {
                const float4* kp = reinterpret_cast<const float4*>(k + ((size_t)j * HKV + kh) * D);
#pragma unroll
                for (int i = 0; i < 8; ++i) {
                    float4 x0 = qp[i * 4 + 0], y0 = kp[i * 4 + 0];
                    float4 x1 = qp[i * 4 + 1], y1 = kp[i * 4 + 1];
                    float4 x2 = qp[i * 4 + 2], y2 = kp[i * 4 + 2];
                    float4 x3 = qp[i * 4 + 3], y3 = kp[i * 4 + 3];
                    a0 += x0.x * y0.x + x0.y * y0.y + x0.z * y0.z + x0.w * y0.w;
                    a1 += x1.x * y1.x + x1.y * y1.y + x1.z * y1.z + x1.w * y1.w;
                    a2 += x2.x * y2.x + x2.y * y2.y + x2.z * y2.z + x2.w * y2.w;
                    a3 += x3.x * y3.x + x3.y * y3.y + x3.z * y3.z + x3.w * y3.w;
                }
            }
            acc = (a0 + a1) + (a2 + a3);
        }
        float sc = ok ? acc * SCALE : NEGF;
        float cm = sc;
#pragma unroll
        for (int off = 32; off; off >>= 1) cm = fmaxf(cm, __shfl_xor(cm, off));
        float mn = fmaxf(m, cm);
        float scale_f = expf(m - mn);
        o0 *= scale_f; o1 *= scale_f; lsum *= scale_f;
        float p = ok ? expf(sc - mn) : 0.f;
        float ps = p;
#pragma unroll
        for (int off = 32; off; off >>= 1) ps += __shfl_xor(ps, off);
        lsum += ps;
        m = mn;
        float c00 = 0.f, c01 = 0.f, c02 = 0.f, c03 = 0.f;
        float c10 = 0.f, c11 = 0.f, c12 = 0.f, c13 = 0.f;
        const float* vbase = v + ((size_t)s * 64 * HKV + kh) * D;
#pragma unroll 4
        for (int nn = 0; nn < 64; nn += 4) {
            float p0 = __shfl(p, nn), p1 = __shfl(p, nn + 1);
            float p2 = __shfl(p, nn + 2), p3 = __shfl(p, nn + 3);
            const float* v0 = vbase + (size_t)(nn + 0) * HKV * D;
            const float* v1 = vbase + (size_t)(nn + 1) * HKV * D;
            const float* v2 = vbase + (size_t)(nn + 2) * HKV * D;
            const float* v3 = vbase + (size_t)(nn + 3) * HKV * D;
            c00 += p0 * v0[d0]; c10 += p0 * v0[d1];
            c01 += p1 * v1[d0]; c11 += p1 * v1[d1];
            c02 += p2 * v2[d0]; c12 += p2 * v2[d1];
            c03 += p3 * v3[d0]; c13 += p3 * v3[d1];
        }
        o0 += (c00 + c01) + (c02 + c03);
        o1 += (c10 + c11) + (c12 + c13);
    };

    if (MODE == 0) {
        unsigned msk = selmask[kh * T + t];
        int c = 0;
        for (int s = 0; s < S; ++s) {
            if (((msk >> s) & 1) && s * SEL <= t) {
                if ((c & 3) == w) process_chunk(s, 0);
                ++c;
            }
        }
    } else {
        int lo = t - WIN + 1;
        if (lo < 0) lo = 0;
        for (int s = lo / 64 + w; s <= t / 64; s += 4) process_chunk(s, lo);
    }

    // ---- merge 4 waves via LDS (exact log-sum-exp combine) ----
    __shared__ float sm[4], sl[4];
    __shared__ float so0[4][64], so1[4][64];
    if (lane == 0) { sm[w] = m; sl[w] = lsum; }
    so0[w][lane] = o0;
    so1[w][lane] = o1;
    __syncthreads();
    if (w == 0) {
        float M = fmaxf(fmaxf(sm[0], sm[1]), fmaxf(sm[2], sm[3]));
        float e0 = expf(sm[0] - M), e1 = expf(sm[1] - M);
        float e2 = expf(sm[2] - M), e3 = expf(sm[3] - M);
        float L = sl[0] * e0 + sl[1] * e1 + sl[2] * e2 + sl[3] * e3;
        float O0 = so0[0][lane] * e0 + so0[1][lane] * e1 + so0[2][lane] * e2 + so0[3][lane] * e3;
        float O1 = so1[0][lane] * e0 + so1[1][lane] * e1 + so1[2][lane] * e2 + so1[3][lane] * e3;
        float inv = 1.f / L;
        float* op = out + ((size_t)t * HQ + h) * D;
        op[d0] = O0 * inv;
        op[d1] = O1 * inv;
    }
}

// ================= gates + combine (wave per (t,h)) ==============
__global__ __launch_bounds__(256)
void gate_wave(const float* __restrict__ q, const float* __restrict__ Wg,
               const float* __restrict__ o_cmp, const float* __restrict__ o_sel,
               const float* __restrict__ o_win, float* __restrict__ o_comb) {
    int wid = blockIdx.x * 4 + (threadIdx.x >> 6);
    int lane = threadIdx.x & 63;
    int t = wid / HQ, h = wid % HQ;
    const float* qp = q + ((size_t)t * HQ + h) * D;
    const float* wg = Wg + (size_t)h * D * 3;
    float g0 = 0.f, g1 = 0.f, g2 = 0.f;
#pragma unroll
    for (int r = 0; r < 2; ++r) {
        int d = lane + r * 64;
        float qv = qp[d];
        g0 += qv * wg[d * 3 + 0];
        g1 += qv * wg[d * 3 + 1];
        g2 += qv * wg[d * 3 + 2];
    }
#pragma unroll
    for (int off = 32; off; off >>= 1) {
        g0 += __shfl_xor(g0, off);
        g1 += __shfl_xor(g1, off);
        g2 += __shfl_xor(g2, off);
    }
    g0 = 1.f / (1.f + expf(-g0));
    g1 = 1.f / (1.f + expf(-g1));
    g2 = 1.f / (1.f + expf(-g2));
    size_t base = ((size_t)t * HQ + h) * D;
#pragma unroll
    for (int r = 0; r < 2; ++r) {
        size_t i = base + lane + r * 64;
        o_comb[i] = g0 * o_cmp[i] + g1 * o_sel[i] + g2 * o_win[i];
    }
}

// ================= launcher ==============
extern "C" void kernel_launch(void* const* d_in, const int* in_sizes, int n_in,
                              void* d_out, int out_size, void* d_ws, size_t ws_size,
                              hipStream_t stream) {
    const float* hs   = (const float*)d_in[0];
    const float* cosb = (const float*)d_in[1];
    const float* sinb = (const float*)d_in[2];
    const float* Wq   = (const float*)d_in[3];
    const float* bq   = (const float*)d_in[4];
    const float* Wk   = (const float*)d_in[5];
    const float* bk   = (const float*)d_in[6];
    const float* Wv   = (const float*)d_in[7];
    const float* bv   = (const float*)d_in[8];
    const float* Wo   = (const float*)d_in[9];
    const float* w_ck = (const float*)d_in[10];
    const float* w_cv = (const float*)d_in[11];
    const float* Wg   = (const float*)d_in[12];
    float* out = (float*)d_out;   // f32 buffer; harness reads high 16 bits as bf16

    float* ws = (float*)d_ws;
    size_t off = 0;
    float* q      = ws + off; off += (size_t)T * HQ * D;
    float* k      = ws + off; off += (size_t)T * HKV * D;
    float* v      = ws + off; off += (size_t)T * HKV * D;
    float* k_cmp  = ws + off; off += (size_t)NC * HKV * D;
    float* v_cmp  = ws + off; off += (size_t)NC * HKV * D;
    float* p_cmp  = ws + off; off += (size_t)HQ * T * NC;
    float* o_cmp  = ws + off; off += (size_t)T * HQ * D;
    float* o_sel  = ws + off; off += (size_t)T * HQ * D;
    float* o_win  = ws + off; off += (size_t)T * HQ * D;
    unsigned* selmask = (unsigned*)(ws + off);

    gemm_tiled<0, true><<<dim3((HQ * D) / BN, T / BM), 256, 0, stream>>>(hs, Wq, bq, q, T, HQ * D, HID);
    gemm_tiled<0, true><<<dim3((HKV * D) / BN, T / BM), 256, 0, stream>>>(hs, Wk, bk, k, T, HKV * D, HID);
    gemm_tiled<0, true><<<dim3((HKV * D) / BN, T / BM), 256, 0, stream>>>(hs, Wv, bv, v, T, HKV * D, HID);
    rope_kernel<<<(T * HQ * 64) / 256, 256, 0, stream>>>(q, cosb, sinb, HQ);
    rope_kernel<<<(T * HKV * 64) / 256, 256, 0, stream>>>(k, cosb, sinb, HKV);
    compress_kernel<<<(NC * HKV * D) / 256, 256, 0, stream>>>(k, v, w_ck, w_cv, k_cmp, v_cmp);
    cmp_attn_wave<<<(T * HQ) / 4, 256, 0, stream>>>(q, k_cmp, v_cmp, p_cmp, o_cmp);
    select_kernel<<<(HKV * T) / 256, 256, 0, stream>>>(p_cmp, selmask);
    attn_block<0><<<T * HQ, 256, 0, stream>>>(q, k, v, selmask, o_sel);
    attn_block<1><<<T * HQ, 256, 0, stream>>>(q, k, v, nullptr, o_win);
    gate_wave<<<(T * HQ) / 4, 256, 0, stream>>>(q, Wg, o_cmp, o_sel, o_win, o_cmp);
    gemm_tiled<1, false><<<dim3(HID / BN, T / BM), 256, 0, stream>>>(o_cmp, Wo, nullptr, out, T, HID, HQ * D);
}

// Round 28
// 1393.913 us; speedup vs baseline: 71.0584x; 2.9227x over previous
//
#include <hip/hip_runtime.h>
#include <hip/hip_bf16.h>

// ---- problem constants ----
constexpr int T = 2048, HID = 2048;
constexpr int HQ = 16, HKV = 2, D = 128, G = 8;
constexpr int KER = 32, SEL = 64, TOPN = 16, WIN = 512;
constexpr int NC = T / KER;
constexpr int S  = T / SEL;
constexpr float SCALE = 0.08838834764831845f;
constexpr float NEGF = -1e30f;

typedef __attribute__((ext_vector_type(8))) __bf16 bf16x8;
typedef __attribute__((ext_vector_type(4))) float f32x4;

__device__ __forceinline__ ushort f2bf(float f) {
    __hip_bfloat16 h = __float2bfloat16(f);
    return *reinterpret_cast<const ushort*>(&h);
}

// ================= tiled NT GEMM (unchanged) =================
#define BM 64
#define BN 64
#define BK 32

template<int OUT_MODE, bool HAS_BIAS>
__global__ __launch_bounds__(256)
void gemm_tiled(const float* __restrict__ A, const float* __restrict__ Bm,
                const float* __restrict__ bias, float* __restrict__ C,
                int M, int N, int K) {
    __shared__ float As[BK][BM + 1];
    __shared__ float Bs[BK][BN + 1];
    const int m0 = blockIdx.y * BM, n0 = blockIdx.x * BN;
    const int tid = threadIdx.x;
    const int tx = tid % 16, ty = tid / 16;
    float acc[4][4] = {};
    for (int k0 = 0; k0 < K; k0 += BK) {
#pragma unroll
        for (int i = 0; i < 2; ++i) {
            int idx = tid + i * 256;
            int r = idx >> 3;
            int c4 = idx & 7;
            float4 a = *reinterpret_cast<const float4*>(&A[(size_t)(m0 + r) * K + k0 + c4 * 4]);
            As[c4 * 4 + 0][r] = a.x; As[c4 * 4 + 1][r] = a.y;
            As[c4 * 4 + 2][r] = a.z; As[c4 * 4 + 3][r] = a.w;
            float4 b = *reinterpret_cast<const float4*>(&Bm[(size_t)(n0 + r) * K + k0 + c4 * 4]);
            Bs[c4 * 4 + 0][r] = b.x; Bs[c4 * 4 + 1][r] = b.y;
            Bs[c4 * 4 + 2][r] = b.z; Bs[c4 * 4 + 3][r] = b.w;
        }
        __syncthreads();
#pragma unroll
        for (int kk = 0; kk < BK; ++kk) {
            float a[4], b[4];
#pragma unroll
            for (int i = 0; i < 4; ++i) a[i] = As[kk][ty * 4 + i];
#pragma unroll
            for (int j = 0; j < 4; ++j) b[j] = Bs[kk][tx * 4 + j];
#pragma unroll
            for (int i = 0; i < 4; ++i)
#pragma unroll
                for (int j = 0; j < 4; ++j) acc[i][j] += a[i] * b[j];
        }
        __syncthreads();
    }
#pragma unroll
    for (int i = 0; i < 4; ++i) {
        int m = m0 + ty * 4 + i;
#pragma unroll
        for (int j = 0; j < 4; ++j) {
            int n = n0 + tx * 4 + j;
            float val = acc[i][j];
            if (HAS_BIAS) val += bias[n];
            if (OUT_MODE == 1) val = __bfloat162float(__float2bfloat16(val));
            C[(size_t)m * N + n] = val;
        }
    }
}

// ================= RoPE (unchanged) ==============
__global__ void rope_kernel(float* __restrict__ x, const float* __restrict__ cosb,
                            const float* __restrict__ sinb, int H) {
    int idx = blockIdx.x * blockDim.x + threadIdx.x;
    if (idx >= T * H * 64) return;
    int d = idx & 63;
    int th = idx >> 6;
    int h = th % H, t = th / H;
    float c0 = cosb[t * D + d],      s0 = sinb[t * D + d];
    float c1 = cosb[t * D + d + 64], s1 = sinb[t * D + d + 64];
    float* p = x + ((size_t)t * H + h) * D;
    float x0 = p[d], x1 = p[d + 64];
    p[d]      = x0 * c0 - x1 * s0;
    p[d + 64] = x1 * c1 + x0 * s1;
}

// ================= f32 -> bf16 buffer conversion ==============
__global__ void to_bf16_kernel(const float* __restrict__ in, ushort* __restrict__ out, int n4) {
    int i = blockIdx.x * 256 + threadIdx.x;
    if (i >= n4) return;
    float4 f = *reinterpret_cast<const float4*>(&in[(size_t)i * 4]);
    ushort4 u;
    u.x = f2bf(f.x); u.y = f2bf(f.y); u.z = f2bf(f.z); u.w = f2bf(f.w);
    *reinterpret_cast<ushort4*>(&out[(size_t)i * 4]) = u;
}

// ================= compression (unchanged) ==============
__global__ void compress_kernel(const float* __restrict__ k, const float* __restrict__ v,
                                const float* __restrict__ wck, const float* __restrict__ wcv,
                                float* __restrict__ k_cmp, float* __restrict__ v_cmp) {
    int idx = blockIdx.x * blockDim.x + threadIdx.x;
    if (idx >= NC * HKV * D) return;
    int d = idx % D;
    int h = (idx / D) % HKV;
    int n = idx / (D * HKV);
    float ak = 0.f, av = 0.f;
#pragma unroll 8
    for (int j = 0; j < KER; ++j) {
        size_t off = ((size_t)(n * KER + j) * HKV + h) * D + d;
        ak += k[off] * wck[j];
        av += v[off] * wcv[j];
    }
    k_cmp[idx] = ak;
    v_cmp[idx] = av;
}

// ================= compressed attention (unchanged) ==============
__global__ __launch_bounds__(256)
void cmp_attn_wave(const float* __restrict__ q, const float* __restrict__ k_cmp,
                   const float* __restrict__ v_cmp, float* __restrict__ p_cmp,
                   float* __restrict__ o_cmp) {
    int wid = blockIdx.x * 4 + (threadIdx.x >> 6);
    int lane = threadIdx.x & 63;
    int t = wid / HQ, h = wid % HQ;
    int kh = h / G;
    int n = lane;
    bool vis = (t >= KER * n + KER - 1);
    const float4* qp = reinterpret_cast<const float4*>(q + ((size_t)t * HQ + h) * D);
    const float4* kp = reinterpret_cast<const float4*>(k_cmp + ((size_t)n * HKV + kh) * D);
    float a0 = 0.f, a1 = 0.f, a2 = 0.f, a3 = 0.f;
#pragma unroll
    for (int i = 0; i < 8; ++i) {
        float4 x0 = qp[i * 4 + 0], y0 = kp[i * 4 + 0];
        float4 x1 = qp[i * 4 + 1], y1 = kp[i * 4 + 1];
        float4 x2 = qp[i * 4 + 2], y2 = kp[i * 4 + 2];
        float4 x3 = qp[i * 4 + 3], y3 = kp[i * 4 + 3];
        a0 += x0.x * y0.x + x0.y * y0.y + x0.z * y0.z + x0.w * y0.w;
        a1 += x1.x * y1.x + x1.y * y1.y + x1.z * y1.z + x1.w * y1.w;
        a2 += x2.x * y2.x + x2.y * y2.y + x2.z * y2.z + x2.w * y2.w;
        a3 += x3.x * y3.x + x3.y * y3.y + x3.z * y3.z + x3.w * y3.w;
    }
    float acc = (a0 + a1) + (a2 + a3);
    float s = vis ? acc * SCALE : NEGF;
    float mx = s;
#pragma unroll
    for (int off = 32; off; off >>= 1) mx = fmaxf(mx, __shfl_xor(mx, off));
    float e = vis ? expf(s - mx) : 0.f;
    float sum = e;
#pragma unroll
    for (int off = 32; off; off >>= 1) sum += __shfl_xor(sum, off);
    float p = (sum > 0.f) ? (e / sum) : 0.f;
    p_cmp[((size_t)h * T + t) * NC + n] = p;
    float c00 = 0.f, c01 = 0.f, c02 = 0.f, c03 = 0.f;
    float c10 = 0.f, c11 = 0.f, c12 = 0.f, c13 = 0.f;
    int d0 = lane, d1 = lane + 64;
    for (int nn = 0; nn < NC; nn += 4) {
        float p0 = __shfl(p, nn), p1 = __shfl(p, nn + 1);
        float p2 = __shfl(p, nn + 2), p3 = __shfl(p, nn + 3);
        const float* v0 = v_cmp + ((size_t)(nn + 0) * HKV + kh) * D;
        const float* v1 = v_cmp + ((size_t)(nn + 1) * HKV + kh) * D;
        const float* v2 = v_cmp + ((size_t)(nn + 2) * HKV + kh) * D;
        const float* v3 = v_cmp + ((size_t)(nn + 3) * HKV + kh) * D;
        c00 += p0 * v0[d0]; c10 += p0 * v0[d1];
        c01 += p1 * v1[d0]; c11 += p1 * v1[d1];
        c02 += p2 * v2[d0]; c12 += p2 * v2[d1];
        c03 += p3 * v3[d0]; c13 += p3 * v3[d1];
    }
    float* op = o_cmp + ((size_t)t * HQ + h) * D;
    op[d0] = (c00 + c01) + (c02 + c03);
    op[d1] = (c10 + c11) + (c12 + c13);
}

// ================= selection (unchanged) ==============
__global__ void select_kernel(const float* __restrict__ p_cmp, unsigned* __restrict__ selmask) {
    int idx = blockIdx.x * blockDim.x + threadIdx.x;
    if (idx >= HKV * T) return;
    int t = idx % T, kh = idx / T;
    float bs[S];
#pragma unroll
    for (int s = 0; s < S; ++s) bs[s] = 0.f;
    for (int g = 0; g < G; ++g) {
        const float* pp = p_cmp + (((size_t)(kh * G + g)) * T + t) * NC;
#pragma unroll
        for (int s = 0; s < S; ++s) bs[s] += pp[2 * s] + pp[2 * s + 1];
    }
    int cur = t / SEL;
#pragma unroll
    for (int s = 0; s < S; ++s) {
        bool vis = (s * SEL <= t);
        bool force = (s == 0) || (s == cur);
        bs[s] = vis ? (bs[s] + (force ? 1e6f : 0.f)) : NEGF;
    }
    unsigned chosen = 0;
    for (int it = 0; it < TOPN; ++it) {
        float best = -3e38f;
        int bj = 0;
#pragma unroll
        for (int s = 0; s < S; ++s) {
            bool free_s = !((chosen >> s) & 1);
            if (free_s && bs[s] > best) { best = bs[s]; bj = s; }
        }
        chosen |= 1u << bj;
    }
    selmask[idx] = chosen;
}

// ======== MFMA flash attention: block = (kh, 16-query tile) x 8 heads (8 waves) ========
// gridDim.x = HKV * (T/16) = 256, gridDim.y = 2 (0 = selected, 1 = window)
__global__ __launch_bounds__(512)
void attn_mfma(const float* __restrict__ qf, const ushort* __restrict__ kb,
               const ushort* __restrict__ vb, const unsigned* __restrict__ selmask,
               float* __restrict__ o_sel, float* __restrict__ o_win) {
    const int mode = blockIdx.y;
    const int kh = blockIdx.x >> 7;
    const int tt = blockIdx.x & 127;
    const int t0 = tt * 16;
    const int w = threadIdx.x >> 6;     // head within group (wave id)
    const int lane = threadIdx.x & 63;
    const int h = kh * G + w;
    const int lx = lane & 15;
    const int lg = lane >> 4;
    const int koff = lg * 8;

    __shared__ ushort VT[128][72];       // transposed V chunk, XOR-swizzled columns
    __shared__ ushort Pl[8][16][72];     // per-wave P tile (16 q x 64 keys)

    // q fragments (A operand): row = query lx, 4 k-slices of 32
    bf16x8 aq[4];
    {
        const float* qrow = qf + ((size_t)(t0 + lx) * HQ + h) * D;
#pragma unroll
        for (int s4 = 0; s4 < 4; ++s4) {
            union { bf16x8 v; ushort u[8]; } tmp;
#pragma unroll
            for (int jj = 0; jj < 8; ++jj) tmp.u[jj] = f2bf(qrow[s4 * 32 + koff + jj]);
            aq[s4] = tmp.v;
        }
    }
    unsigned mskj[4] = {0, 0, 0, 0};
    unsigned un = 0;
    if (mode == 0) {
#pragma unroll
        for (int j = 0; j < 4; ++j) {
            mskj[j] = selmask[kh * T + t0 + lg * 4 + j];
            un |= mskj[j];
        }
        un |= __shfl_xor(un, 16);
        un |= __shfl_xor(un, 32);
    }
    int smax = (t0 + 15) / 64;
    int smin = 0;
    if (mode == 1) {
        int lo = t0 - (WIN - 1);
        if (lo < 0) lo = 0;
        smin = lo / 64;
    }

    float m_run[4], l_run[4];
    f32x4 oacc[8];
#pragma unroll
    for (int j = 0; j < 4; ++j) { m_run[j] = NEGF; l_run[j] = 0.f; }
#pragma unroll
    for (int ds = 0; ds < 8; ++ds)
#pragma unroll
        for (int j = 0; j < 4; ++j) oacc[ds][j] = 0.f;

    for (int s = smin; s <= smax; ++s) {
        if (mode == 0 && !((un >> s) & 1u)) continue;   // block-uniform skip
        __syncthreads();
        // ---- stage V chunk transposed into LDS (swizzled) ----
        {
            int i = threadIdx.x;
            int key = i >> 3;
            int d0 = (i & 7) * 16;
            const ushort* src = vb + ((size_t)(s * 64 + key) * HKV + kh) * D + d0;
            union { uint4 q; ushort u[8]; } r0, r1;
            r0.q = *reinterpret_cast<const uint4*>(src);
            r1.q = *reinterpret_cast<const uint4*>(src + 8);
            int kcol = key ^ (((d0 >> 4) & 7) << 3);
#pragma unroll
            for (int e = 0; e < 8; ++e) VT[d0 + e][kcol] = r0.u[e];
#pragma unroll
            for (int e = 0; e < 8; ++e) VT[d0 + 8 + e][kcol] = r1.u[e];
        }
        __syncthreads();
        // ---- QK^T: 4 key-subtiles x 4 k-slices ----
        f32x4 sc[4];
#pragma unroll
        for (int ks = 0; ks < 4; ++ks)
#pragma unroll
            for (int j = 0; j < 4; ++j) sc[ks][j] = 0.f;
#pragma unroll
        for (int ks = 0; ks < 4; ++ks) {
            const ushort* kbase = kb + ((size_t)(s * 64 + ks * 16 + lx) * HKV + kh) * D;
#pragma unroll
            for (int s4 = 0; s4 < 4; ++s4) {
                bf16x8 bk = *reinterpret_cast<const bf16x8*>(kbase + s4 * 32 + koff);
                sc[ks] = __builtin_amdgcn_mfma_f32_16x16x32_bf16(aq[s4], bk, sc[ks], 0, 0, 0);
            }
        }
        // ---- mask + online softmax (C layout: col=lx=key, row=lg*4+j) ----
#pragma unroll
        for (int ks = 0; ks < 4; ++ks) {
            int key = s * 64 + ks * 16 + lx;
#pragma unroll
            for (int j = 0; j < 4; ++j) {
                int trow = t0 + lg * 4 + j;
                bool valid = (key <= trow) &&
                             (mode ? (key >= trow - (WIN - 1)) : (((mskj[j] >> s) & 1u) != 0));
                sc[ks][j] = valid ? sc[ks][j] * SCALE : NEGF;
            }
        }
#pragma unroll
        for (int j = 0; j < 4; ++j) {
            float mj = fmaxf(fmaxf(sc[0][j], sc[1][j]), fmaxf(sc[2][j], sc[3][j]));
            mj = fmaxf(mj, __shfl_xor(mj, 1));
            mj = fmaxf(mj, __shfl_xor(mj, 2));
            mj = fmaxf(mj, __shfl_xor(mj, 4));
            mj = fmaxf(mj, __shfl_xor(mj, 8));
            float mn = fmaxf(m_run[j], mj);
            float scl = expf(m_run[j] - mn);
            l_run[j] *= scl;
#pragma unroll
            for (int ds = 0; ds < 8; ++ds) oacc[ds][j] *= scl;
            float rs = 0.f;
#pragma unroll
            for (int ks = 0; ks < 4; ++ks) {
                float x = sc[ks][j];
                float p = (x < -1e29f) ? 0.f : expf(x - mn);
                sc[ks][j] = p;
                rs += p;
            }
            rs += __shfl_xor(rs, 1);
            rs += __shfl_xor(rs, 2);
            rs += __shfl_xor(rs, 4);
            rs += __shfl_xor(rs, 8);
            l_run[j] += rs;
            m_run[j] = mn;
        }
        // ---- P -> LDS (bf16), then PV via MFMA ----
#pragma unroll
        for (int ks = 0; ks < 4; ++ks)
#pragma unroll
            for (int j = 0; j < 4; ++j)
                Pl[w][lg * 4 + j][ks * 16 + lx] = f2bf(sc[ks][j]);
        __syncthreads();
#pragma unroll
        for (int sl = 0; sl < 2; ++sl) {
            bf16x8 ap = *reinterpret_cast<const bf16x8*>(&Pl[w][lx][sl * 32 + koff]);
#pragma unroll
            for (int ds = 0; ds < 8; ++ds) {
                int col = (sl * 32 + koff) ^ (ds << 3);
                bf16x8 bv = *reinterpret_cast<const bf16x8*>(&VT[ds * 16 + lx][col]);
                oacc[ds] = __builtin_amdgcn_mfma_f32_16x16x32_bf16(ap, bv, oacc[ds], 0, 0, 0);
            }
        }
    }
    // ---- epilogue ----
    float* optr = mode ? o_win : o_sel;
    float inv[4];
#pragma unroll
    for (int j = 0; j < 4; ++j) inv[j] = 1.f / l_run[j];
#pragma unroll
    for (int ds = 0; ds < 8; ++ds)
#pragma unroll
        for (int j = 0; j < 4; ++j) {
            int row = lg * 4 + j;
            int d = ds * 16 + lx;
            optr[((size_t)(t0 + row) * HQ + h) * D + d] = oacc[ds][j] * inv[j];
        }
}

// ================= gates + combine (unchanged) ==============
__global__ __launch_bounds__(256)
void gate_wave(const float* __restrict__ q, const float* __restrict__ Wg,
               const float* __restrict__ o_cmp, const float* __restrict__ o_sel,
               const float* __restrict__ o_win, float* __restrict__ o_comb) {
    int wid = blockIdx.x * 4 + (threadIdx.x >> 6);
    int lane = threadIdx.x & 63;
    int t = wid / HQ, h = wid % HQ;
    const float* qp = q + ((size_t)t * HQ + h) * D;
    const float* wg = Wg + (size_t)h * D * 3;
    float g0 = 0.f, g1 = 0.f, g2 = 0.f;
#pragma unroll
    for (int r = 0; r < 2; ++r) {
        int d = lane + r * 64;
        float qv = qp[d];
        g0 += qv * wg[d * 3 + 0];
        g1 += qv * wg[d * 3 + 1];
        g2 += qv * wg[d * 3 + 2];
    }
#pragma unroll
    for (int off = 32; off; off >>= 1) {
        g0 += __shfl_xor(g0, off);
        g1 += __shfl_xor(g1, off);
        g2 += __shfl_xor(g2, off);
    }
    g0 = 1.f / (1.f + expf(-g0));
    g1 = 1.f / (1.f + expf(-g1));
    g2 = 1.f / (1.f + expf(-g2));
    size_t base = ((size_t)t * HQ + h) * D;
#pragma unroll
    for (int r = 0; r < 2; ++r) {
        size_t i = base + lane + r * 64;
        o_comb[i] = g0 * o_cmp[i] + g1 * o_sel[i] + g2 * o_win[i];
    }
}

// ================= launcher ==============
extern "C" void kernel_launch(void* const* d_in, const int* in_sizes, int n_in,
                              void* d_out, int out_size, void* d_ws, size_t ws_size,
                              hipStream_t stream) {
    const float* hs   = (const float*)d_in[0];
    const float* cosb = (const float*)d_in[1];
    const float* sinb = (const float*)d_in[2];
    const float* Wq   = (const float*)d_in[3];
    const float* bq   = (const float*)d_in[4];
    const float* Wk   = (const float*)d_in[5];
    const float* bk   = (const float*)d_in[6];
    const float* Wv   = (const float*)d_in[7];
    const float* bv   = (const float*)d_in[8];
    const float* Wo   = (const float*)d_in[9];
    const float* w_ck = (const float*)d_in[10];
    const float* w_cv = (const float*)d_in[11];
    const float* Wg   = (const float*)d_in[12];
    float* out = (float*)d_out;   // f32 buffer; harness reads high 16 bits as bf16

    float* ws = (float*)d_ws;
    size_t off = 0;
    float* q      = ws + off; off += (size_t)T * HQ * D;
    float* k      = ws + off; off += (size_t)T * HKV * D;
    float* v      = ws + off; off += (size_t)T * HKV * D;
    float* k_cmp  = ws + off; off += (size_t)NC * HKV * D;
    float* v_cmp  = ws + off; off += (size_t)NC * HKV * D;
    float* p_cmp  = ws + off; off += (size_t)HQ * T * NC;
    float* o_cmp  = ws + off; off += (size_t)T * HQ * D;
    float* o_sel  = ws + off; off += (size_t)T * HQ * D;
    float* o_win  = ws + off; off += (size_t)T * HQ * D;
    unsigned* selmask = (unsigned*)(ws + off); off += HKV * T;
    ushort* kb = (ushort*)(ws + off);                    // bf16 k: T*HKV*D ushorts
    ushort* vb = kb + (size_t)T * HKV * D;               // bf16 v

    gemm_tiled<0, true><<<dim3((HQ * D) / BN, T / BM), 256, 0, stream>>>(hs, Wq, bq, q, T, HQ * D, HID);
    gemm_tiled<0, true><<<dim3((HKV * D) / BN, T / BM), 256, 0, stream>>>(hs, Wk, bk, k, T, HKV * D, HID);
    gemm_tiled<0, true><<<dim3((HKV * D) / BN, T / BM), 256, 0, stream>>>(hs, Wv, bv, v, T, HKV * D, HID);
    rope_kernel<<<(T * HQ * 64) / 256, 256, 0, stream>>>(q, cosb, sinb, HQ);
    rope_kernel<<<(T * HKV * 64) / 256, 256, 0, stream>>>(k, cosb, sinb, HKV);
    // bf16 copies of k and v for MFMA attention
    to_bf16_kernel<<<(T * HKV * D / 4 + 255) / 256, 256, 0, stream>>>(k, kb, T * HKV * D / 4);
    to_bf16_kernel<<<(T * HKV * D / 4 + 255) / 256, 256, 0, stream>>>(v, vb, T * HKV * D / 4);
    compress_kernel<<<(NC * HKV * D) / 256, 256, 0, stream>>>(k, v, w_ck, w_cv, k_cmp, v_cmp);
    cmp_attn_wave<<<(T * HQ) / 4, 256, 0, stream>>>(q, k_cmp, v_cmp, p_cmp, o_cmp);
    select_kernel<<<(HKV * T) / 256, 256, 0, stream>>>(p_cmp, selmask);
    // MFMA flash attention: selected (y=0) + window (y=1)
    attn_mfma<<<dim3(HKV * (T / 16), 2), 512, 0, stream>>>(q, kb, vb, selmask, o_sel, o_win);
    gate_wave<<<(T * HQ) / 4, 256, 0, stream>>>(q, Wg, o_cmp, o_sel, o_win, o_cmp);
    gemm_tiled<1, false><<<dim3(HID / BN, T / BM), 256, 0, stream>>>(o_cmp, Wo, nullptr, out, T, HID, HQ * D);
}

// Round 30
// 728.356 us; speedup vs baseline: 135.9902x; 1.9138x over previous
//
#include <hip/hip_runtime.h>
#include <hip/hip_bf16.h>

// ---- problem constants ----
constexpr int T = 2048, HID = 2048;
constexpr int HQ = 16, HKV = 2, D = 128, G = 8;
constexpr int KER = 32, SEL = 64, TOPN = 16, WIN = 512;
constexpr int NC = T / KER;
constexpr int S  = T / SEL;
constexpr float SCALE = 0.08838834764831845f;
constexpr float NEGF = -1e30f;

typedef __attribute__((ext_vector_type(8))) __bf16 bf16x8;
typedef __attribute__((ext_vector_type(4))) float f32x4;

__device__ __forceinline__ ushort f2bf(float f) {
    __hip_bfloat16 h = __float2bfloat16(f);
    return *reinterpret_cast<const ushort*>(&h);
}

// ================= f32 -> bf16 buffer conversion ==============
__global__ void to_bf16_kernel(const float* __restrict__ in, ushort* __restrict__ out, int n4) {
    int i = blockIdx.x * 256 + threadIdx.x;
    if (i >= n4) return;
    float4 f = *reinterpret_cast<const float4*>(&in[(size_t)i * 4]);
    ushort4 u;
    u.x = f2bf(f.x); u.y = f2bf(f.y); u.z = f2bf(f.z); u.w = f2bf(f.w);
    *reinterpret_cast<ushort4*>(&out[(size_t)i * 4]) = u;
}

// ========== bf16 MFMA GEMM: C[M,N] = A[M,K] @ B[N,K]^T (+bias), f32 out ==========
// tile 128x128, BK=32, 4 waves in 2x2, each wave 64x64 = 4x4 fragments of 16x16x32.
template<int OUT_MODE, bool HAS_BIAS>
__global__ __launch_bounds__(256)
void gemm_mfma(const ushort* __restrict__ A, const ushort* __restrict__ B,
               const float* __restrict__ bias, float* __restrict__ C,
               int M, int N, int K) {
    __shared__ ushort As[128][40];
    __shared__ ushort Bs[128][40];
    const int m0 = blockIdx.y * 128, n0 = blockIdx.x * 128;
    const int tid = threadIdx.x;
    const int w = tid >> 6, lane = tid & 63;
    const int wr = (w >> 1) * 64, wc = (w & 1) * 64;
    const int lx = lane & 15, lg = lane >> 4;
    f32x4 acc[4][4];
#pragma unroll
    for (int mi = 0; mi < 4; ++mi)
#pragma unroll
        for (int ni = 0; ni < 4; ++ni)
#pragma unroll
            for (int j = 0; j < 4; ++j) acc[mi][ni][j] = 0.f;

    for (int k0 = 0; k0 < K; k0 += 32) {
        {   // stage A,B tiles: thread -> (row r, 16-elem half) via TWO uint4 (8 ushorts each)
            int r = tid >> 1, half = (tid & 1) * 16;
            const ushort* ap = A + (size_t)(m0 + r) * K + k0 + half;
            const ushort* bp = B + (size_t)(n0 + r) * K + k0 + half;
            *reinterpret_cast<uint4*>(&As[r][half])     = *reinterpret_cast<const uint4*>(ap);
            *reinterpret_cast<uint4*>(&As[r][half + 8]) = *reinterpret_cast<const uint4*>(ap + 8);
            *reinterpret_cast<uint4*>(&Bs[r][half])     = *reinterpret_cast<const uint4*>(bp);
            *reinterpret_cast<uint4*>(&Bs[r][half + 8]) = *reinterpret_cast<const uint4*>(bp + 8);
        }
        __syncthreads();
        bf16x8 af[4], bfr[4];
#pragma unroll
        for (int mi = 0; mi < 4; ++mi)
            af[mi] = *reinterpret_cast<const bf16x8*>(&As[wr + mi * 16 + lx][lg * 8]);
#pragma unroll
        for (int ni = 0; ni < 4; ++ni)
            bfr[ni] = *reinterpret_cast<const bf16x8*>(&Bs[wc + ni * 16 + lx][lg * 8]);
#pragma unroll
        for (int mi = 0; mi < 4; ++mi)
#pragma unroll
            for (int ni = 0; ni < 4; ++ni)
                acc[mi][ni] = __builtin_amdgcn_mfma_f32_16x16x32_bf16(af[mi], bfr[ni], acc[mi][ni], 0, 0, 0);
        __syncthreads();
    }
#pragma unroll
    for (int mi = 0; mi < 4; ++mi)
#pragma unroll
        for (int ni = 0; ni < 4; ++ni)
#pragma unroll
            for (int j = 0; j < 4; ++j) {
                int m = m0 + wr + mi * 16 + lg * 4 + j;
                int n = n0 + wc + ni * 16 + lx;
                float val = acc[mi][ni][j];
                if (HAS_BIAS) val += bias[n];
                if (OUT_MODE == 1) val = __bfloat162float(__float2bfloat16(val));
                C[(size_t)m * N + n] = val;
            }
}

// ================= RoPE (in-place) ==============
__global__ void rope_kernel(float* __restrict__ x, const float* __restrict__ cosb,
                            const float* __restrict__ sinb, int H) {
    int idx = blockIdx.x * blockDim.x + threadIdx.x;
    if (idx >= T * H * 64) return;
    int d = idx & 63;
    int th = idx >> 6;
    int h = th % H, t = th / H;
    float c0 = cosb[t * D + d],      s0 = sinb[t * D + d];
    float c1 = cosb[t * D + d + 64], s1 = sinb[t * D + d + 64];
    float* p = x + ((size_t)t * H + h) * D;
    float x0 = p[d], x1 = p[d + 64];
    p[d]      = x0 * c0 - x1 * s0;
    p[d + 64] = x1 * c1 + x0 * s1;
}

// ================= compression ==============
__global__ void compress_kernel(const float* __restrict__ k, const float* __restrict__ v,
                                const float* __restrict__ wck, const float* __restrict__ wcv,
                                float* __restrict__ k_cmp, float* __restrict__ v_cmp) {
    int idx = blockIdx.x * blockDim.x + threadIdx.x;
    if (idx >= NC * HKV * D) return;
    int d = idx % D;
    int h = (idx / D) % HKV;
    int n = idx / (D * HKV);
    float ak = 0.f, av = 0.f;
#pragma unroll 8
    for (int j = 0; j < KER; ++j) {
        size_t off = ((size_t)(n * KER + j) * HKV + h) * D + d;
        ak += k[off] * wck[j];
        av += v[off] * wcv[j];
    }
    k_cmp[idx] = ak;
    v_cmp[idx] = av;
}

// ================= compressed attention (wave per (t,h)) ==============
__global__ __launch_bounds__(256)
void cmp_attn_wave(const float* __restrict__ q, const float* __restrict__ k_cmp,
                   const float* __restrict__ v_cmp, float* __restrict__ p_cmp,
                   float* __restrict__ o_cmp) {
    int wid = blockIdx.x * 4 + (threadIdx.x >> 6);
    int lane = threadIdx.x & 63;
    int t = wid / HQ, h = wid % HQ;
    int kh = h / G;
    int n = lane;
    bool vis = (t >= KER * n + KER - 1);
    const float4* qp = reinterpret_cast<const float4*>(q + ((size_t)t * HQ + h) * D);
    const float4* kp = reinterpret_cast<const float4*>(k_cmp + ((size_t)n * HKV + kh) * D);
    float a0 = 0.f, a1 = 0.f, a2 = 0.f, a3 = 0.f;
#pragma unroll
    for (int i = 0; i < 8; ++i) {
        float4 x0 = qp[i * 4 + 0], y0 = kp[i * 4 + 0];
        float4 x1 = qp[i * 4 + 1], y1 = kp[i * 4 + 1];
        float4 x2 = qp[i * 4 + 2], y2 = kp[i * 4 + 2];
        float4 x3 = qp[i * 4 + 3], y3 = kp[i * 4 + 3];
        a0 += x0.x * y0.x + x0.y * y0.y + x0.z * y0.z + x0.w * y0.w;
        a1 += x1.x * y1.x + x1.y * y1.y + x1.z * y1.z + x1.w * y1.w;
        a2 += x2.x * y2.x + x2.y * y2.y + x2.z * y2.z + x2.w * y2.w;
        a3 += x3.x * y3.x + x3.y * y3.y + x3.z * y3.z + x3.w * y3.w;
    }
    float acc = (a0 + a1) + (a2 + a3);
    float s = vis ? acc * SCALE : NEGF;
    float mx = s;
#pragma unroll
    for (int off = 32; off; off >>= 1) mx = fmaxf(mx, __shfl_xor(mx, off));
    float e = vis ? expf(s - mx) : 0.f;
    float sum = e;
#pragma unroll
    for (int off = 32; off; off >>= 1) sum += __shfl_xor(sum, off);
    float p = (sum > 0.f) ? (e / sum) : 0.f;
    p_cmp[((size_t)h * T + t) * NC + n] = p;
    float c00 = 0.f, c01 = 0.f, c02 = 0.f, c03 = 0.f;
    float c10 = 0.f, c11 = 0.f, c12 = 0.f, c13 = 0.f;
    int d0 = lane, d1 = lane + 64;
    for (int nn = 0; nn < NC; nn += 4) {
        float p0 = __shfl(p, nn), p1 = __shfl(p, nn + 1);
        float p2 = __shfl(p, nn + 2), p3 = __shfl(p, nn + 3);
        const float* v0 = v_cmp + ((size_t)(nn + 0) * HKV + kh) * D;
        const float* v1 = v_cmp + ((size_t)(nn + 1) * HKV + kh) * D;
        const float* v2 = v_cmp + ((size_t)(nn + 2) * HKV + kh) * D;
        const float* v3 = v_cmp + ((size_t)(nn + 3) * HKV + kh) * D;
        c00 += p0 * v0[d0]; c10 += p0 * v0[d1];
        c01 += p1 * v1[d0]; c11 += p1 * v1[d1];
        c02 += p2 * v2[d0]; c12 += p2 * v2[d1];
        c03 += p3 * v3[d0]; c13 += p3 * v3[d1];
    }
    float* op = o_cmp + ((size_t)t * HQ + h) * D;
    op[d0] = (c00 + c01) + (c02 + c03);
    op[d1] = (c10 + c11) + (c12 + c13);
}

// ================= selection ==============
__global__ void select_kernel(const float* __restrict__ p_cmp, unsigned* __restrict__ selmask) {
    int idx = blockIdx.x * blockDim.x + threadIdx.x;
    if (idx >= HKV * T) return;
    int t = idx % T, kh = idx / T;
    float bs[S];
#pragma unroll
    for (int s = 0; s < S; ++s) bs[s] = 0.f;
    for (int g = 0; g < G; ++g) {
        const float* pp = p_cmp + (((size_t)(kh * G + g)) * T + t) * NC;
#pragma unroll
        for (int s = 0; s < S; ++s) bs[s] += pp[2 * s] + pp[2 * s + 1];
    }
    int cur = t / SEL;
#pragma unroll
    for (int s = 0; s < S; ++s) {
        bool vis = (s * SEL <= t);
        bool force = (s == 0) || (s == cur);
        bs[s] = vis ? (bs[s] + (force ? 1e6f : 0.f)) : NEGF;
    }
    unsigned chosen = 0;
    for (int it = 0; it < TOPN; ++it) {
        float best = -3e38f;
        int bj = 0;
#pragma unroll
        for (int s = 0; s < S; ++s) {
            bool free_s = !((chosen >> s) & 1);
            if (free_s && bs[s] > best) { best = bs[s]; bj = s; }
        }
        chosen |= 1u << bj;
    }
    selmask[idx] = chosen;
}

// ======== MFMA flash attention (unchanged, validated R28) ========
__global__ __launch_bounds__(512)
void attn_mfma(const float* __restrict__ qf, const ushort* __restrict__ kb,
               const ushort* __restrict__ vb, const unsigned* __restrict__ selmask,
               float* __restrict__ o_sel, float* __restrict__ o_win) {
    const int mode = blockIdx.y;
    const int kh = blockIdx.x >> 7;
    const int tt = blockIdx.x & 127;
    const int t0 = tt * 16;
    const int w = threadIdx.x >> 6;
    const int lane = threadIdx.x & 63;
    const int h = kh * G + w;
    const int lx = lane & 15;
    const int lg = lane >> 4;
    const int koff = lg * 8;

    __shared__ ushort VT[128][72];
    __shared__ ushort Pl[8][16][72];

    bf16x8 aq[4];
    {
        const float* qrow = qf + ((size_t)(t0 + lx) * HQ + h) * D;
#pragma unroll
        for (int s4 = 0; s4 < 4; ++s4) {
            union { bf16x8 v; ushort u[8]; } tmp;
#pragma unroll
            for (int jj = 0; jj < 8; ++jj) tmp.u[jj] = f2bf(qrow[s4 * 32 + koff + jj]);
            aq[s4] = tmp.v;
        }
    }
    unsigned mskj[4] = {0, 0, 0, 0};
    unsigned un = 0;
    if (mode == 0) {
#pragma unroll
        for (int j = 0; j < 4; ++j) {
            mskj[j] = selmask[kh * T + t0 + lg * 4 + j];
            un |= mskj[j];
        }
        un |= __shfl_xor(un, 16);
        un |= __shfl_xor(un, 32);
    }
    int smax = (t0 + 15) / 64;
    int smin = 0;
    if (mode == 1) {
        int lo = t0 - (WIN - 1);
        if (lo < 0) lo = 0;
        smin = lo / 64;
    }

    float m_run[4], l_run[4];
    f32x4 oacc[8];
#pragma unroll
    for (int j = 0; j < 4; ++j) { m_run[j] = NEGF; l_run[j] = 0.f; }
#pragma unroll
    for (int ds = 0; ds < 8; ++ds)
#pragma unroll
        for (int j = 0; j < 4; ++j) oacc[ds][j] = 0.f;

    for (int s = smin; s <= smax; ++s) {
        if (mode == 0 && !((un >> s) & 1u)) continue;
        __syncthreads();
        {
            int i = threadIdx.x;
            int key = i >> 3;
            int d0 = (i & 7) * 16;
            const ushort* src = vb + ((size_t)(s * 64 + key) * HKV + kh) * D + d0;
            union { uint4 q; ushort u[8]; } r0, r1;
            r0.q = *reinterpret_cast<const uint4*>(src);
            r1.q = *reinterpret_cast<const uint4*>(src + 8);
            int kcol = key ^ (((d0 >> 4) & 7) << 3);
#pragma unroll
            for (int e = 0; e < 8; ++e) VT[d0 + e][kcol] = r0.u[e];
#pragma unroll
            for (int e = 0; e < 8; ++e) VT[d0 + 8 + e][kcol] = r1.u[e];
        }
        __syncthreads();
        f32x4 sc[4];
#pragma unroll
        for (int ks = 0; ks < 4; ++ks)
#pragma unroll
            for (int j = 0; j < 4; ++j) sc[ks][j] = 0.f;
#pragma unroll
        for (int ks = 0; ks < 4; ++ks) {
            const ushort* kbase = kb + ((size_t)(s * 64 + ks * 16 + lx) * HKV + kh) * D;
#pragma unroll
            for (int s4 = 0; s4 < 4; ++s4) {
                bf16x8 bk = *reinterpret_cast<const bf16x8*>(kbase + s4 * 32 + koff);
                sc[ks] = __builtin_amdgcn_mfma_f32_16x16x32_bf16(aq[s4], bk, sc[ks], 0, 0, 0);
            }
        }
#pragma unroll
        for (int ks = 0; ks < 4; ++ks) {
            int key = s * 64 + ks * 16 + lx;
#pragma unroll
            for (int j = 0; j < 4; ++j) {
                int trow = t0 + lg * 4 + j;
                bool valid = (key <= trow) &&
                             (mode ? (key >= trow - (WIN - 1)) : (((mskj[j] >> s) & 1u) != 0));
                sc[ks][j] = valid ? sc[ks][j] * SCALE : NEGF;
            }
        }
#pragma unroll
        for (int j = 0; j < 4; ++j) {
            float mj = fmaxf(fmaxf(sc[0][j], sc[1][j]), fmaxf(sc[2][j], sc[3][j]));
            mj = fmaxf(mj, __shfl_xor(mj, 1));
            mj = fmaxf(mj, __shfl_xor(mj, 2));
            mj = fmaxf(mj, __shfl_xor(mj, 4));
            mj = fmaxf(mj, __shfl_xor(mj, 8));
            float mn = fmaxf(m_run[j], mj);
            float scl = expf(m_run[j] - mn);
            l_run[j] *= scl;
#pragma unroll
            for (int ds = 0; ds < 8; ++ds) oacc[ds][j] *= scl;
            float rs = 0.f;
#pragma unroll
            for (int ks = 0; ks < 4; ++ks) {
                float x = sc[ks][j];
                float p = (x < -1e29f) ? 0.f : expf(x - mn);
                sc[ks][j] = p;
                rs += p;
            }
            rs += __shfl_xor(rs, 1);
            rs += __shfl_xor(rs, 2);
            rs += __shfl_xor(rs, 4);
            rs += __shfl_xor(rs, 8);
            l_run[j] += rs;
            m_run[j] = mn;
        }
#pragma unroll
        for (int ks = 0; ks < 4; ++ks)
#pragma unroll
            for (int j = 0; j < 4; ++j)
                Pl[w][lg * 4 + j][ks * 16 + lx] = f2bf(sc[ks][j]);
        __syncthreads();
#pragma unroll
        for (int sl = 0; sl < 2; ++sl) {
            bf16x8 ap = *reinterpret_cast<const bf16x8*>(&Pl[w][lx][sl * 32 + koff]);
#pragma unroll
            for (int ds = 0; ds < 8; ++ds) {
                int col = (sl * 32 + koff) ^ (ds << 3);
                bf16x8 bv = *reinterpret_cast<const bf16x8*>(&VT[ds * 16 + lx][col]);
                oacc[ds] = __builtin_amdgcn_mfma_f32_16x16x32_bf16(ap, bv, oacc[ds], 0, 0, 0);
            }
        }
    }
    float* optr = mode ? o_win : o_sel;
    float inv[4];
#pragma unroll
    for (int j = 0; j < 4; ++j) inv[j] = 1.f / l_run[j];
#pragma unroll
    for (int ds = 0; ds < 8; ++ds)
#pragma unroll
        for (int j = 0; j < 4; ++j) {
            int row = lg * 4 + j;
            int d = ds * 16 + lx;
            optr[((size_t)(t0 + row) * HQ + h) * D + d] = oacc[ds][j] * inv[j];
        }
}

// ================= gates + combine ==============
__global__ __launch_bounds__(256)
void gate_wave(const float* __restrict__ q, const float* __restrict__ Wg,
               const float* __restrict__ o_cmp, const float* __restrict__ o_sel,
               const float* __restrict__ o_win, float* __restrict__ o_comb) {
    int wid = blockIdx.x * 4 + (threadIdx.x >> 6);
    int lane = threadIdx.x & 63;
    int t = wid / HQ, h = wid % HQ;
    const float* qp = q + ((size_t)t * HQ + h) * D;
    const float* wg = Wg + (size_t)h * D * 3;
    float g0 = 0.f, g1 = 0.f, g2 = 0.f;
#pragma unroll
    for (int r = 0; r < 2; ++r) {
        int d = lane + r * 64;
        float qv = qp[d];
        g0 += qv * wg[d * 3 + 0];
        g1 += qv * wg[d * 3 + 1];
        g2 += qv * wg[d * 3 + 2];
    }
#pragma unroll
    for (int off = 32; off; off >>= 1) {
        g0 += __shfl_xor(g0, off);
        g1 += __shfl_xor(g1, off);
        g2 += __shfl_xor(g2, off);
    }
    g0 = 1.f / (1.f + expf(-g0));
    g1 = 1.f / (1.f + expf(-g1));
    g2 = 1.f / (1.f + expf(-g2));
    size_t base = ((size_t)t * HQ + h) * D;
#pragma unroll
    for (int r = 0; r < 2; ++r) {
        size_t i = base + lane + r * 64;
        o_comb[i] = g0 * o_cmp[i] + g1 * o_sel[i] + g2 * o_win[i];
    }
}

// ================= launcher ==============
extern "C" void kernel_launch(void* const* d_in, const int* in_sizes, int n_in,
                              void* d_out, int out_size, void* d_ws, size_t ws_size,
                              hipStream_t stream) {
    const float* hs   = (const float*)d_in[0];
    const float* cosb = (const float*)d_in[1];
    const float* sinb = (const float*)d_in[2];
    const float* Wq   = (const float*)d_in[3];
    const float* bq   = (const float*)d_in[4];
    const float* Wk   = (const float*)d_in[5];
    const float* bk   = (const float*)d_in[6];
    const float* Wv   = (const float*)d_in[7];
    const float* bv   = (const float*)d_in[8];
    const float* Wo   = (const float*)d_in[9];
    const float* w_ck = (const float*)d_in[10];
    const float* w_cv = (const float*)d_in[11];
    const float* Wg   = (const float*)d_in[12];
    float* out = (float*)d_out;   // f32 buffer; harness reads high 16 bits as bf16

    float* ws = (float*)d_ws;
    size_t off = 0;
    float* q      = ws + off; off += (size_t)T * HQ * D;
    float* k      = ws + off; off += (size_t)T * HKV * D;
    float* v      = ws + off; off += (size_t)T * HKV * D;
    float* k_cmp  = ws + off; off += (size_t)NC * HKV * D;
    float* v_cmp  = ws + off; off += (size_t)NC * HKV * D;
    float* p_cmp  = ws + off; off += (size_t)HQ * T * NC;
    float* o_cmp  = ws + off; off += (size_t)T * HQ * D;
    float* o_sel  = ws + off; off += (size_t)T * HQ * D;
    float* o_win  = ws + off; off += (size_t)T * HQ * D;
    unsigned* selmask = (unsigned*)(ws + off); off += HKV * T;
    ushort* kb = (ushort*)(ws + off);
    ushort* vb = kb + (size_t)T * HKV * D;

    // bf16 scratch aliased into dead-at-time-of-use regions:
    ushort* hs_b = (ushort*)p_cmp;
    ushort* Wq_b = (ushort*)o_cmp;
    ushort* Wk_b = (ushort*)o_sel;
    ushort* Wv_b = Wk_b + (size_t)HKV * D * HID;
    ushort* Wo_b = (ushort*)o_sel;
    ushort* oc_b = (ushort*)o_win;

    const int NQ = HQ * D, NKVd = HKV * D;

    to_bf16_kernel<<<(T * HID / 4) / 256, 256, 0, stream>>>(hs, hs_b, T * HID / 4);
    to_bf16_kernel<<<(NQ * HID / 4) / 256, 256, 0, stream>>>(Wq, Wq_b, NQ * HID / 4);
    to_bf16_kernel<<<(NKVd * HID / 4) / 256, 256, 0, stream>>>(Wk, Wk_b, NKVd * HID / 4);
    to_bf16_kernel<<<(NKVd * HID / 4) / 256, 256, 0, stream>>>(Wv, Wv_b, NKVd * HID / 4);
    gemm_mfma<0, true><<<dim3(NQ / 128, T / 128), 256, 0, stream>>>(hs_b, Wq_b, bq, q, T, NQ, HID);
    gemm_mfma<0, true><<<dim3(NKVd / 128, T / 128), 256, 0, stream>>>(hs_b, Wk_b, bk, k, T, NKVd, HID);
    gemm_mfma<0, true><<<dim3(NKVd / 128, T / 128), 256, 0, stream>>>(hs_b, Wv_b, bv, v, T, NKVd, HID);
    rope_kernel<<<(T * HQ * 64) / 256, 256, 0, stream>>>(q, cosb, sinb, HQ);
    rope_kernel<<<(T * HKV * 64) / 256, 256, 0, stream>>>(k, cosb, sinb, HKV);
    to_bf16_kernel<<<(T * HKV * D / 4 + 255) / 256, 256, 0, stream>>>(k, kb, T * HKV * D / 4);
    to_bf16_kernel<<<(T * HKV * D / 4 + 255) / 256, 256, 0, stream>>>(v, vb, T * HKV * D / 4);
    compress_kernel<<<(NC * HKV * D) / 256, 256, 0, stream>>>(k, v, w_ck, w_cv, k_cmp, v_cmp);
    cmp_attn_wave<<<(T * HQ) / 4, 256, 0, stream>>>(q, k_cmp, v_cmp, p_cmp, o_cmp);
    select_kernel<<<(HKV * T) / 256, 256, 0, stream>>>(p_cmp, selmask);
    attn_mfma<<<dim3(HKV * (T / 16), 2), 512, 0, stream>>>(q, kb, vb, selmask, o_sel, o_win);
    gate_wave<<<(T * HQ) / 4, 256, 0, stream>>>(q, Wg, o_cmp, o_sel, o_win, o_cmp);
    to_bf16_kernel<<<(T * NQ / 4) / 256, 256, 0, stream>>>(o_cmp, oc_b, T * NQ / 4);
    to_bf16_kernel<<<(HID * NQ / 4) / 256, 256, 0, stream>>>(Wo, Wo_b, HID * NQ / 4);
    gemm_mfma<1, false><<<dim3(HID / 128, T / 128), 256, 0, stream>>>(oc_b, Wo_b, nullptr, out, T, HID, NQ);
}

// Round 31
// 691.998 us; speedup vs baseline: 143.1352x; 1.0525x over previous
//
#include <hip/hip_runtime.h>
#include <hip/hip_bf16.h>

// ---- problem constants ----
constexpr int T = 2048, HID = 2048;
constexpr int HQ = 16, HKV = 2, D = 128, G = 8;
constexpr int KER = 32, SEL = 64, TOPN = 16, WIN = 512;
constexpr int NC = T / KER;
constexpr int S  = T / SEL;
constexpr float SCALE = 0.08838834764831845f;
constexpr float NEGF = -1e30f;

typedef __attribute__((ext_vector_type(8))) __bf16 bf16x8;
typedef __attribute__((ext_vector_type(4))) float f32x4;

__device__ __forceinline__ ushort f2bf(float f) {
    __hip_bfloat16 h = __float2bfloat16(f);
    return *reinterpret_cast<const ushort*>(&h);
}

// ================= f32 -> bf16 buffer conversion ==============
__global__ void to_bf16_kernel(const float* __restrict__ in, ushort* __restrict__ out, int n4) {
    int i = blockIdx.x * 256 + threadIdx.x;
    if (i >= n4) return;
    float4 f = *reinterpret_cast<const float4*>(&in[(size_t)i * 4]);
    ushort4 u;
    u.x = f2bf(f.x); u.y = f2bf(f.y); u.z = f2bf(f.z); u.w = f2bf(f.w);
    *reinterpret_cast<ushort4*>(&out[(size_t)i * 4]) = u;
}

// ========== bf16 MFMA GEMM (validated R30) ==========
template<int OUT_MODE, bool HAS_BIAS>
__global__ __launch_bounds__(256)
void gemm_mfma(const ushort* __restrict__ A, const ushort* __restrict__ B,
               const float* __restrict__ bias, float* __restrict__ C,
               int M, int N, int K) {
    __shared__ ushort As[128][40];
    __shared__ ushort Bs[128][40];
    const int m0 = blockIdx.y * 128, n0 = blockIdx.x * 128;
    const int tid = threadIdx.x;
    const int w = tid >> 6, lane = tid & 63;
    const int wr = (w >> 1) * 64, wc = (w & 1) * 64;
    const int lx = lane & 15, lg = lane >> 4;
    f32x4 acc[4][4];
#pragma unroll
    for (int mi = 0; mi < 4; ++mi)
#pragma unroll
        for (int ni = 0; ni < 4; ++ni)
#pragma unroll
            for (int j = 0; j < 4; ++j) acc[mi][ni][j] = 0.f;

    for (int k0 = 0; k0 < K; k0 += 32) {
        {
            int r = tid >> 1, half = (tid & 1) * 16;
            const ushort* ap = A + (size_t)(m0 + r) * K + k0 + half;
            const ushort* bp = B + (size_t)(n0 + r) * K + k0 + half;
            *reinterpret_cast<uint4*>(&As[r][half])     = *reinterpret_cast<const uint4*>(ap);
            *reinterpret_cast<uint4*>(&As[r][half + 8]) = *reinterpret_cast<const uint4*>(ap + 8);
            *reinterpret_cast<uint4*>(&Bs[r][half])     = *reinterpret_cast<const uint4*>(bp);
            *reinterpret_cast<uint4*>(&Bs[r][half + 8]) = *reinterpret_cast<const uint4*>(bp + 8);
        }
        __syncthreads();
        bf16x8 af[4], bfr[4];
#pragma unroll
        for (int mi = 0; mi < 4; ++mi)
            af[mi] = *reinterpret_cast<const bf16x8*>(&As[wr + mi * 16 + lx][lg * 8]);
#pragma unroll
        for (int ni = 0; ni < 4; ++ni)
            bfr[ni] = *reinterpret_cast<const bf16x8*>(&Bs[wc + ni * 16 + lx][lg * 8]);
#pragma unroll
        for (int mi = 0; mi < 4; ++mi)
#pragma unroll
            for (int ni = 0; ni < 4; ++ni)
                acc[mi][ni] = __builtin_amdgcn_mfma_f32_16x16x32_bf16(af[mi], bfr[ni], acc[mi][ni], 0, 0, 0);
        __syncthreads();
    }
#pragma unroll
    for (int mi = 0; mi < 4; ++mi)
#pragma unroll
        for (int ni = 0; ni < 4; ++ni)
#pragma unroll
            for (int j = 0; j < 4; ++j) {
                int m = m0 + wr + mi * 16 + lg * 4 + j;
                int n = n0 + wc + ni * 16 + lx;
                float val = acc[mi][ni][j];
                if (HAS_BIAS) val += bias[n];
                if (OUT_MODE == 1) val = __bfloat162float(__float2bfloat16(val));
                C[(size_t)m * N + n] = val;
            }
}

// ================= RoPE (in-place) ==============
__global__ void rope_kernel(float* __restrict__ x, const float* __restrict__ cosb,
                            const float* __restrict__ sinb, int H) {
    int idx = blockIdx.x * blockDim.x + threadIdx.x;
    if (idx >= T * H * 64) return;
    int d = idx & 63;
    int th = idx >> 6;
    int h = th % H, t = th / H;
    float c0 = cosb[t * D + d],      s0 = sinb[t * D + d];
    float c1 = cosb[t * D + d + 64], s1 = sinb[t * D + d + 64];
    float* p = x + ((size_t)t * H + h) * D;
    float x0 = p[d], x1 = p[d + 64];
    p[d]      = x0 * c0 - x1 * s0;
    p[d + 64] = x1 * c1 + x0 * s1;
}

// ================= compression ==============
__global__ void compress_kernel(const float* __restrict__ k, const float* __restrict__ v,
                                const float* __restrict__ wck, const float* __restrict__ wcv,
                                float* __restrict__ k_cmp, float* __restrict__ v_cmp) {
    int idx = blockIdx.x * blockDim.x + threadIdx.x;
    if (idx >= NC * HKV * D) return;
    int d = idx % D;
    int h = (idx / D) % HKV;
    int n = idx / (D * HKV);
    float ak = 0.f, av = 0.f;
#pragma unroll 8
    for (int j = 0; j < KER; ++j) {
        size_t off = ((size_t)(n * KER + j) * HKV + h) * D + d;
        ak += k[off] * wck[j];
        av += v[off] * wcv[j];
    }
    k_cmp[idx] = ak;
    v_cmp[idx] = av;
}

// ================= compressed attention (wave per (t,h)) ==============
__global__ __launch_bounds__(256)
void cmp_attn_wave(const float* __restrict__ q, const float* __restrict__ k_cmp,
                   const float* __restrict__ v_cmp, float* __restrict__ p_cmp,
                   float* __restrict__ o_cmp) {
    int wid = blockIdx.x * 4 + (threadIdx.x >> 6);
    int lane = threadIdx.x & 63;
    int t = wid / HQ, h = wid % HQ;
    int kh = h / G;
    int n = lane;
    bool vis = (t >= KER * n + KER - 1);
    const float4* qp = reinterpret_cast<const float4*>(q + ((size_t)t * HQ + h) * D);
    const float4* kp = reinterpret_cast<const float4*>(k_cmp + ((size_t)n * HKV + kh) * D);
    float a0 = 0.f, a1 = 0.f, a2 = 0.f, a3 = 0.f;
#pragma unroll
    for (int i = 0; i < 8; ++i) {
        float4 x0 = qp[i * 4 + 0], y0 = kp[i * 4 + 0];
        float4 x1 = qp[i * 4 + 1], y1 = kp[i * 4 + 1];
        float4 x2 = qp[i * 4 + 2], y2 = kp[i * 4 + 2];
        float4 x3 = qp[i * 4 + 3], y3 = kp[i * 4 + 3];
        a0 += x0.x * y0.x + x0.y * y0.y + x0.z * y0.z + x0.w * y0.w;
        a1 += x1.x * y1.x + x1.y * y1.y + x1.z * y1.z + x1.w * y1.w;
        a2 += x2.x * y2.x + x2.y * y2.y + x2.z * y2.z + x2.w * y2.w;
        a3 += x3.x * y3.x + x3.y * y3.y + x3.z * y3.z + x3.w * y3.w;
    }
    float acc = (a0 + a1) + (a2 + a3);
    float s = vis ? acc * SCALE : NEGF;
    float mx = s;
#pragma unroll
    for (int off = 32; off; off >>= 1) mx = fmaxf(mx, __shfl_xor(mx, off));
    float e = vis ? expf(s - mx) : 0.f;
    float sum = e;
#pragma unroll
    for (int off = 32; off; off >>= 1) sum += __shfl_xor(sum, off);
    float p = (sum > 0.f) ? (e / sum) : 0.f;
    p_cmp[((size_t)h * T + t) * NC + n] = p;
    float c00 = 0.f, c01 = 0.f, c02 = 0.f, c03 = 0.f;
    float c10 = 0.f, c11 = 0.f, c12 = 0.f, c13 = 0.f;
    int d0 = lane, d1 = lane + 64;
    for (int nn = 0; nn < NC; nn += 4) {
        float p0 = __shfl(p, nn), p1 = __shfl(p, nn + 1);
        float p2 = __shfl(p, nn + 2), p3 = __shfl(p, nn + 3);
        const float* v0 = v_cmp + ((size_t)(nn + 0) * HKV + kh) * D;
        const float* v1 = v_cmp + ((size_t)(nn + 1) * HKV + kh) * D;
        const float* v2 = v_cmp + ((size_t)(nn + 2) * HKV + kh) * D;
        const float* v3 = v_cmp + ((size_t)(nn + 3) * HKV + kh) * D;
        c00 += p0 * v0[d0]; c10 += p0 * v0[d1];
        c01 += p1 * v1[d0]; c11 += p1 * v1[d1];
        c02 += p2 * v2[d0]; c12 += p2 * v2[d1];
        c03 += p3 * v3[d0]; c13 += p3 * v3[d1];
    }
    float* op = o_cmp + ((size_t)t * HQ + h) * D;
    op[d0] = (c00 + c01) + (c02 + c03);
    op[d1] = (c10 + c11) + (c12 + c13);
}

// ================= selection (re-gridded: 64 blocks x 64 threads) ==============
__global__ void select_kernel(const float* __restrict__ p_cmp, unsigned* __restrict__ selmask) {
    int idx = blockIdx.x * 64 + threadIdx.x;
    if (idx >= HKV * T) return;
    int t = idx % T, kh = idx / T;
    float bs[S];
#pragma unroll
    for (int s = 0; s < S; ++s) bs[s] = 0.f;
    for (int g = 0; g < G; ++g) {
        const float* pp = p_cmp + (((size_t)(kh * G + g)) * T + t) * NC;
#pragma unroll
        for (int s = 0; s < S; ++s) bs[s] += pp[2 * s] + pp[2 * s + 1];
    }
    int cur = t / SEL;
#pragma unroll
    for (int s = 0; s < S; ++s) {
        bool vis = (s * SEL <= t);
        bool force = (s == 0) || (s == cur);
        bs[s] = vis ? (bs[s] + (force ? 1e6f : 0.f)) : NEGF;
    }
    unsigned chosen = 0;
    for (int it = 0; it < TOPN; ++it) {
        float best = -3e38f;
        int bj = 0;
#pragma unroll
        for (int s = 0; s < S; ++s) {
            bool free_s = !((chosen >> s) & 1);
            if (free_s && bs[s] > best) { best = bs[s]; bj = s; }
        }
        chosen |= 1u << bj;
    }
    selmask[idx] = chosen;
}

// ================= V transpose: vbt[kh][d][t] = vb[t][kh][d] ==============
__global__ void transpose_v(const ushort* __restrict__ vb, ushort* __restrict__ vbt) {
    __shared__ ushort tl[32][33];
    int kh = blockIdx.z, t0 = blockIdx.x * 32, d0 = blockIdx.y * 32;
    int tx = threadIdx.x, ty = threadIdx.y;
    for (int r = ty; r < 32; r += 8)
        tl[r][tx] = vb[(size_t)(t0 + r) * (HKV * D) + kh * D + d0 + tx];
    __syncthreads();
    for (int r = ty; r < 32; r += 8)
        vbt[((size_t)kh * D + d0 + r) * T + t0 + tx] = tl[tx][r];
}

// ======== FUSED MFMA flash attention: sel + win share QK^T and staging ========
// grid.x = HKV * 2(head-half) * (T/16) = 512 blocks; 4 waves = 4 heads.
__global__ __launch_bounds__(256)
void attn_fused(const float* __restrict__ qf, const ushort* __restrict__ kb,
                const ushort* __restrict__ vbt, const unsigned* __restrict__ selmask,
                float* __restrict__ o_sel, float* __restrict__ o_win) {
    const int bid = blockIdx.x;
    const int kh = bid >> 8;
    const int rest = bid & 255;
    const int hh = rest >> 7;
    const int tt = rest & 127;
    const int t0 = tt * 16;
    const int w = threadIdx.x >> 6;
    const int lane = threadIdx.x & 63;
    const int h = kh * G + hh * 4 + w;
    const int lx = lane & 15, lg = lane >> 4, koff = lg * 8;

    __shared__ ushort Ks[64][136];    // K chunk, row-major (keys x D); stride 272B -> 2-way (free)
    __shared__ ushort VT[128][72];    // V^T chunk (d x keys), from global vbt; stride 144B -> 2-way
    __shared__ ushort Pl[4][16][72];  // per-wave P tile

    // q fragments
    bf16x8 aq[4];
    {
        const float* qrow = qf + ((size_t)(t0 + lx) * HQ + h) * D;
#pragma unroll
        for (int s4 = 0; s4 < 4; ++s4) {
            union { bf16x8 v; ushort u[8]; } tmp;
#pragma unroll
            for (int jj = 0; jj < 8; ++jj) tmp.u[jj] = f2bf(qrow[s4 * 32 + koff + jj]);
            aq[s4] = tmp.v;
        }
    }
    unsigned mskj[4];
    unsigned un = 0;
#pragma unroll
    for (int j = 0; j < 4; ++j) {
        mskj[j] = selmask[kh * T + t0 + lg * 4 + j];
        un |= mskj[j];
    }
    un |= __shfl_xor(un, 16);
    un |= __shfl_xor(un, 32);

    int wlo_t = t0 - (WIN - 1); if (wlo_t < 0) wlo_t = 0;
    const int swin_min = wlo_t / 64;
    const int smax = (t0 + 15) / 64;

    float msel[4], lsel[4], mwin[4], lwin[4];
    f32x4 osel[8], owin[8];
#pragma unroll
    for (int j = 0; j < 4; ++j) { msel[j] = NEGF; lsel[j] = 0.f; mwin[j] = NEGF; lwin[j] = 0.f; }
#pragma unroll
    for (int ds = 0; ds < 8; ++ds)
#pragma unroll
        for (int j = 0; j < 4; ++j) { osel[ds][j] = 0.f; owin[ds][j] = 0.f; }

    for (int s = 0; s <= smax; ++s) {
        const bool selA = (un >> s) & 1u;
        const bool winA = (s >= swin_min);
        if (!selA && !winA) continue;
        __syncthreads();
        {   // stage K: 64 rows x 128 ushorts, vectorized
            int row = threadIdx.x >> 2, seg = threadIdx.x & 3;
            const ushort* src = kb + ((size_t)(s * 64 + row) * HKV + kh) * D + seg * 32;
            uint4* dst = reinterpret_cast<uint4*>(&Ks[row][seg * 32]);
            const uint4* sp = reinterpret_cast<const uint4*>(src);
            dst[0] = sp[0]; dst[1] = sp[1]; dst[2] = sp[2]; dst[3] = sp[3];
        }
        {   // stage V^T: 128 rows x 64 ushorts, vectorized from global vbt
            int row = threadIdx.x >> 1, seg = threadIdx.x & 1;
            const ushort* src = vbt + ((size_t)kh * D + row) * T + s * 64 + seg * 32;
            uint4* dst = reinterpret_cast<uint4*>(&VT[row][seg * 32]);
            const uint4* sp = reinterpret_cast<const uint4*>(src);
            dst[0] = sp[0]; dst[1] = sp[1]; dst[2] = sp[2]; dst[3] = sp[3];
        }
        __syncthreads();
        // ---- shared QK^T ----
        f32x4 sc[4];
#pragma unroll
        for (int ks = 0; ks < 4; ++ks) {
#pragma unroll
            for (int j = 0; j < 4; ++j) sc[ks][j] = 0.f;
#pragma unroll
            for (int s4 = 0; s4 < 4; ++s4) {
                bf16x8 bk = *reinterpret_cast<const bf16x8*>(&Ks[ks * 16 + lx][s4 * 32 + koff]);
                sc[ks] = __builtin_amdgcn_mfma_f32_16x16x32_bf16(aq[s4], bk, sc[ks], 0, 0, 0);
            }
        }
        // ---- per-mode: mask + online softmax + PV ----
        auto run_mode = [&](float* m_run, float* l_run, f32x4* oa, bool isWin) {
            float pv[4][4];
#pragma unroll
            for (int ks = 0; ks < 4; ++ks) {
                int key = s * 64 + ks * 16 + lx;
#pragma unroll
                for (int j = 0; j < 4; ++j) {
                    int trow = t0 + lg * 4 + j;
                    bool valid = (key <= trow) &&
                                 (isWin ? (key >= trow - (WIN - 1)) : (((mskj[j] >> s) & 1u) != 0));
                    pv[ks][j] = valid ? sc[ks][j] * SCALE : NEGF;
                }
            }
#pragma unroll
            for (int j = 0; j < 4; ++j) {
                float mj = fmaxf(fmaxf(pv[0][j], pv[1][j]), fmaxf(pv[2][j], pv[3][j]));
                mj = fmaxf(mj, __shfl_xor(mj, 1));
                mj = fmaxf(mj, __shfl_xor(mj, 2));
                mj = fmaxf(mj, __shfl_xor(mj, 4));
                mj = fmaxf(mj, __shfl_xor(mj, 8));
                float mn = fmaxf(m_run[j], mj);
                float scl = expf(m_run[j] - mn);
                l_run[j] *= scl;
#pragma unroll
                for (int ds = 0; ds < 8; ++ds) oa[ds][j] *= scl;
                float rs = 0.f;
#pragma unroll
                for (int ks = 0; ks < 4; ++ks) {
                    float x = pv[ks][j];
                    float p = (x < -1e29f) ? 0.f : expf(x - mn);
                    pv[ks][j] = p;
                    rs += p;
                }
                rs += __shfl_xor(rs, 1);
                rs += __shfl_xor(rs, 2);
                rs += __shfl_xor(rs, 4);
                rs += __shfl_xor(rs, 8);
                l_run[j] += rs;
                m_run[j] = mn;
            }
#pragma unroll
            for (int ks = 0; ks < 4; ++ks)
#pragma unroll
                for (int j = 0; j < 4; ++j)
                    Pl[w][lg * 4 + j][ks * 16 + lx] = f2bf(pv[ks][j]);
            // per-wave tile: no block barrier needed (intra-wave LDS ordering)
#pragma unroll
            for (int sl = 0; sl < 2; ++sl) {
                bf16x8 ap = *reinterpret_cast<const bf16x8*>(&Pl[w][lx][sl * 32 + koff]);
#pragma unroll
                for (int ds = 0; ds < 8; ++ds) {
                    bf16x8 bv = *reinterpret_cast<const bf16x8*>(&VT[ds * 16 + lx][sl * 32 + koff]);
                    oa[ds] = __builtin_amdgcn_mfma_f32_16x16x32_bf16(ap, bv, oa[ds], 0, 0, 0);
                }
            }
        };
        if (selA) run_mode(msel, lsel, osel, false);
        if (winA) run_mode(mwin, lwin, owin, true);
    }
    // ---- epilogue ----
    float isel[4], iwin[4];
#pragma unroll
    for (int j = 0; j < 4; ++j) { isel[j] = 1.f / lsel[j]; iwin[j] = 1.f / lwin[j]; }
#pragma unroll
    for (int ds = 0; ds < 8; ++ds)
#pragma unroll
        for (int j = 0; j < 4; ++j) {
            int row = lg * 4 + j;
            int d = ds * 16 + lx;
            size_t o = ((size_t)(t0 + row) * HQ + h) * D + d;
            o_sel[o] = osel[ds][j] * isel[j];
            o_win[o] = owin[ds][j] * iwin[j];
        }
}

// ================= gates + combine ==============
__global__ __launch_bounds__(256)
void gate_wave(const float* __restrict__ q, const float* __restrict__ Wg,
               const float* __restrict__ o_cmp, const float* __restrict__ o_sel,
               const float* __restrict__ o_win, float* __restrict__ o_comb) {
    int wid = blockIdx.x * 4 + (threadIdx.x >> 6);
    int lane = threadIdx.x & 63;
    int t = wid / HQ, h = wid % HQ;
    const float* qp = q + ((size_t)t * HQ + h) * D;
    const float* wg = Wg + (size_t)h * D * 3;
    float g0 = 0.f, g1 = 0.f, g2 = 0.f;
#pragma unroll
    for (int r = 0; r < 2; ++r) {
        int d = lane + r * 64;
        float qv = qp[d];
        g0 += qv * wg[d * 3 + 0];
        g1 += qv * wg[d * 3 + 1];
        g2 += qv * wg[d * 3 + 2];
    }
#pragma unroll
    for (int off = 32; off; off >>= 1) {
        g0 += __shfl_xor(g0, off);
        g1 += __shfl_xor(g1, off);
        g2 += __shfl_xor(g2, off);
    }
    g0 = 1.f / (1.f + expf(-g0));
    g1 = 1.f / (1.f + expf(-g1));
    g2 = 1.f / (1.f + expf(-g2));
    size_t base = ((size_t)t * HQ + h) * D;
#pragma unroll
    for (int r = 0; r < 2; ++r) {
        size_t i = base + lane + r * 64;
        o_comb[i] = g0 * o_cmp[i] + g1 * o_sel[i] + g2 * o_win[i];
    }
}

// ================= launcher ==============
extern "C" void kernel_launch(void* const* d_in, const int* in_sizes, int n_in,
                              void* d_out, int out_size, void* d_ws, size_t ws_size,
                              hipStream_t stream) {
    const float* hs   = (const float*)d_in[0];
    const float* cosb = (const float*)d_in[1];
    const float* sinb = (const float*)d_in[2];
    const float* Wq   = (const float*)d_in[3];
    const float* bq   = (const float*)d_in[4];
    const float* Wk   = (const float*)d_in[5];
    const float* bk   = (const float*)d_in[6];
    const float* Wv   = (const float*)d_in[7];
    const float* bv   = (const float*)d_in[8];
    const float* Wo   = (const float*)d_in[9];
    const float* w_ck = (const float*)d_in[10];
    const float* w_cv = (const float*)d_in[11];
    const float* Wg   = (const float*)d_in[12];
    float* out = (float*)d_out;   // f32 buffer; harness reads high 16 bits as bf16

    float* ws = (float*)d_ws;
    size_t off = 0;
    float* q      = ws + off; off += (size_t)T * HQ * D;
    float* k      = ws + off; off += (size_t)T * HKV * D;
    float* v      = ws + off; off += (size_t)T * HKV * D;
    float* k_cmp  = ws + off; off += (size_t)NC * HKV * D;
    float* v_cmp  = ws + off; off += (size_t)NC * HKV * D;
    float* p_cmp  = ws + off; off += (size_t)HQ * T * NC;
    float* o_cmp  = ws + off; off += (size_t)T * HQ * D;
    float* o_sel  = ws + off; off += (size_t)T * HQ * D;
    float* o_win  = ws + off; off += (size_t)T * HQ * D;
    unsigned* selmask = (unsigned*)(ws + off); off += HKV * T;
    ushort* kb = (ushort*)(ws + off);
    ushort* vb = kb + (size_t)T * HKV * D;

    // aliases into dead-at-time-of-use regions:
    ushort* hs_b = (ushort*)p_cmp;          // dead once cmp_attn writes p_cmp
    ushort* Wq_b = (ushort*)o_cmp;
    ushort* Wk_b = (ushort*)o_sel;
    ushort* Wv_b = Wk_b + (size_t)HKV * D * HID;
    ushort* vbt  = (ushort*)p_cmp;          // after select, p_cmp dead -> holds V^T
    ushort* Wo_b = (ushort*)o_sel;          // after gate
    ushort* oc_b = (ushort*)o_win;          // after gate

    const int NQ = HQ * D, NKVd = HKV * D;

    to_bf16_kernel<<<(T * HID / 4) / 256, 256, 0, stream>>>(hs, hs_b, T * HID / 4);
    to_bf16_kernel<<<(NQ * HID / 4) / 256, 256, 0, stream>>>(Wq, Wq_b, NQ * HID / 4);
    to_bf16_kernel<<<(NKVd * HID / 4) / 256, 256, 0, stream>>>(Wk, Wk_b, NKVd * HID / 4);
    to_bf16_kernel<<<(NKVd * HID / 4) / 256, 256, 0, stream>>>(Wv, Wv_b, NKVd * HID / 4);
    gemm_mfma<0, true><<<dim3(NQ / 128, T / 128), 256, 0, stream>>>(hs_b, Wq_b, bq, q, T, NQ, HID);
    gemm_mfma<0, true><<<dim3(NKVd / 128, T / 128), 256, 0, stream>>>(hs_b, Wk_b, bk, k, T, NKVd, HID);
    gemm_mfma<0, true><<<dim3(NKVd / 128, T / 128), 256, 0, stream>>>(hs_b, Wv_b, bv, v, T, NKVd, HID);
    rope_kernel<<<(T * HQ * 64) / 256, 256, 0, stream>>>(q, cosb, sinb, HQ);
    rope_kernel<<<(T * HKV * 64) / 256, 256, 0, stream>>>(k, cosb, sinb, HKV);
    to_bf16_kernel<<<(T * HKV * D / 4 + 255) / 256, 256, 0, stream>>>(k, kb, T * HKV * D / 4);
    to_bf16_kernel<<<(T * HKV * D / 4 + 255) / 256, 256, 0, stream>>>(v, vb, T * HKV * D / 4);
    compress_kernel<<<(NC * HKV * D) / 256, 256, 0, stream>>>(k, v, w_ck, w_cv, k_cmp, v_cmp);
    cmp_attn_wave<<<(T * HQ) / 4, 256, 0, stream>>>(q, k_cmp, v_cmp, p_cmp, o_cmp);
    select_kernel<<<(HKV * T) / 64, 64, 0, stream>>>(p_cmp, selmask);
    // p_cmp now dead -> build V^T there, then fused attention
    transpose_v<<<dim3(T / 32, D / 32, HKV), dim3(32, 8), 0, stream>>>(vb, vbt);
    attn_fused<<<HKV * 2 * (T / 16), 256, 0, stream>>>(q, kb, vbt, selmask, o_sel, o_win);
    gate_wave<<<(T * HQ) / 4, 256, 0, stream>>>(q, Wg, o_cmp, o_sel, o_win, o_cmp);
    to_bf16_kernel<<<(T * NQ / 4) / 256, 256, 0, stream>>>(o_cmp, oc_b, T * NQ / 4);
    to_bf16_kernel<<<(HID * NQ / 4) / 256, 256, 0, stream>>>(Wo, Wo_b, HID * NQ / 4);
    gemm_mfma<1, false><<<dim3(HID / 128, T / 128), 256, 0, stream>>>(oc_b, Wo_b, nullptr, out, T, HID, NQ);
}